// Round 12
// baseline (110.025 us; speedup 1.0000x reference)
//
#include <hip/hip_runtime.h>
#include <hip/hip_bf16.h>

// Problem constants: B=4, S=512, N=2048, E=1024, QL=32, H=8, D=2, VL=32
// Inputs: 0 embeddings[4,512,1024] 1 keys[4,2048,256] 2 values[4,2048,256]
//         3 ocs[8,1024,2048] 4 Wq[512,1024] 5 bq[512] 6 Wo[1024,512] 7 bo[1024]
//         8 gamma[512] 9 beta[512]       all float32.  Output [4,512,1024] f32.

typedef short  short8 __attribute__((ext_vector_type(8)));
typedef float  f32x4  __attribute__((ext_vector_type(4)));

__device__ __forceinline__ ushort f2bf(float x) {
  union { float f; unsigned int u; } v; v.f = x;
  unsigned int r = v.u + 0x7fffu + ((v.u >> 16) & 1u);
  return (ushort)(r >> 16);
}

// hardware packed f32x2 -> bf16x2 (RNE), 1 instr. Used ONLY where the
// consumer is a DS/shuffle/store op (never directly feeding MFMA).
__device__ __forceinline__ unsigned int cvtpk(float a, float b) {
  unsigned int r;
  asm("v_cvt_pk_bf16_f32 %0, %1, %2" : "=v"(r) : "v"(a), "v"(b));
  return r;
}
__device__ __forceinline__ short8 cvt8(f32x4 a, f32x4 b) {
  union { unsigned int u[4]; short8 s; } r;
  r.u[0] = cvtpk(a[0], a[1]);
  r.u[1] = cvtpk(a[2], a[3]);
  r.u[2] = cvtpk(b[0], b[1]);
  r.u[3] = cvtpk(b[2], b[3]);
  return r.s;
}

#if __has_builtin(__builtin_amdgcn_global_load_lds)
#define OCS_ASYNC 1
__device__ __forceinline__ void gl_lds16(const float* g, float* l) {
  __builtin_amdgcn_global_load_lds(
      (const __attribute__((address_space(1))) unsigned int*)g,
      (__attribute__((address_space(3))) unsigned int*)l, 16, 0, 0);
}
#else
#define OCS_ASYNC 0
#endif

// ---------------------------------------------------------------------------
// prep: keys[b,n,ql*8+h] -> kbf[b,h,n',ql] (bf16) where within each 32-row
// tile, position p = 16s+4gg+r holds source row sigma(p) = 8gg+4s+r. This
// makes the QK^T MFMA output land directly in the K=32 PV B-fragment order
// (lane g holds n = 8g+0..3 from sc0 and 8g+4..7 from sc1) -- no shuffles.
// values[b,n,vl*8+h] -> vbf[b,h,vl,n] (unpermuted).
// ---------------------------------------------------------------------------
__global__ __launch_bounds__(256) void prep_kv(
    const float* __restrict__ keys, const float* __restrict__ values,
    ushort* __restrict__ kbf, ushort* __restrict__ vbf)
{
  __shared__ ushort T[32][264];
  const int bi = blockIdx.x;            // 0..255
  const int b  = bi >> 6;
  const int n0 = (bi & 63) * 32;
  const int t  = threadIdx.x;
  const int nr = t >> 3;                // 0..31
  const int c0 = (t & 7) * 32;          // 0..224

  {
    const float* src = keys + ((size_t)b*2048 + n0 + nr)*256 + c0;
#pragma unroll
    for (int j = 0; j < 32; j += 8) {
      f32x4 x0 = *(const f32x4*)(src + j);
      f32x4 x1 = *(const f32x4*)(src + j + 4);
      *(short8*)&T[nr][c0 + j] = cvt8(x0, x1);
    }
  }
  __syncthreads();
  {
    const int h = t >> 5, nn = t & 31;
    // inverse permutation: source row nn -> tile position pp
    const int pp = 16*((nn >> 2) & 1) + 4*(nn >> 3) + (nn & 3);
    ushort* dst = kbf + (((size_t)(b*8 + h) * 2048) + n0 + pp) * 32;
#pragma unroll
    for (int j = 0; j < 4; j++) {
      short8 w;
#pragma unroll
      for (int i = 0; i < 8; i++) w[i] = (short)T[nn][(j*8 + i)*8 + h];
      *(short8*)(dst + j*8) = w;
    }
  }
  __syncthreads();
  {
    const float* src = values + ((size_t)b*2048 + n0 + nr)*256 + c0;
#pragma unroll
    for (int j = 0; j < 32; j += 8) {
      f32x4 x0 = *(const f32x4*)(src + j);
      f32x4 x1 = *(const f32x4*)(src + j + 4);
      *(short8*)&T[nr][c0 + j] = cvt8(x0, x1);
    }
  }
  __syncthreads();
  {
    const int c = t, h = c & 7, vl = c >> 3;
    ushort* dst = vbf + (((size_t)(b*8 + h) * 32) + vl) * 2048 + n0;
#pragma unroll
    for (int j = 0; j < 4; j++) {
      short8 w;
#pragma unroll
      for (int i = 0; i < 8; i++) w[i] = (short)T[j*8 + i][c];
      *(short8*)(dst + j*8) = w;
    }
  }
}

// ---------------------------------------------------------------------------
// GEMM (NT): out[m,n] = sum_k A[m,k]*B[n,k] + bias[n]. 64x64 tile, 4 waves.
// EPI=0: scatter-store bf16*(1/sqrt(32)) into qbf[b,h,t,ql]; EPI=1: f32 out.
// ---------------------------------------------------------------------------
template<int EPI>
__global__ __launch_bounds__(256) void gemm_nt(
    const float* __restrict__ A, const float* __restrict__ Bm,
    const float* __restrict__ bias, void* __restrict__ outp,
    int M, int N, int K)
{
  __shared__ ushort As[64][32];
  __shared__ ushort Bs[64][32];
  const int tid = threadIdx.x;
  const int m0 = blockIdx.x * 64;
  const int n0 = blockIdx.y * 64;
  const int lane = tid & 63;
  const int wid  = tid >> 6;
  const int wm = wid >> 1, wn = wid & 1;
  const int lt = lane & 15, g = lane >> 4;
  const int lrow = tid >> 2;      // 0..63
  const int lseg = tid & 3;       // 0..3 (8 floats each)
  const int slot_w = lseg ^ ((lrow & 3) ^ ((lrow >> 2) & 3));

  f32x4 acc[2][2] = {};

  for (int k0 = 0; k0 < K; k0 += 32) {
    {
      const float* sa = A + (size_t)(m0 + lrow) * K + k0 + lseg * 8;
      f32x4 a0 = *(const f32x4*)sa;
      f32x4 a1 = *(const f32x4*)(sa + 4);
      *(short8*)&As[lrow][slot_w * 8] = cvt8(a0, a1);
      const float* sb = Bm + (size_t)(n0 + lrow) * K + k0 + lseg * 8;
      f32x4 b0 = *(const f32x4*)sb;
      f32x4 b1 = *(const f32x4*)(sb + 4);
      *(short8*)&Bs[lrow][slot_w * 8] = cvt8(b0, b1);
    }
    __syncthreads();
    short8 af[2], bfr[2];
#pragma unroll
    for (int ss = 0; ss < 2; ss++) {
      const int ra = wm*32 + ss*16 + lt;
      af[ss]  = *(const short8*)&As[ra][(g ^ ((ra & 3) ^ ((ra >> 2) & 3))) * 8];
      const int rb = wn*32 + ss*16 + lt;
      bfr[ss] = *(const short8*)&Bs[rb][(g ^ ((rb & 3) ^ ((rb >> 2) & 3))) * 8];
    }
#pragma unroll
    for (int i = 0; i < 2; i++)
#pragma unroll
      for (int j = 0; j < 2; j++)
        acc[i][j] = __builtin_amdgcn_mfma_f32_16x16x32_bf16(af[i], bfr[j], acc[i][j], 0, 0, 0);
    __syncthreads();
  }

#pragma unroll
  for (int i = 0; i < 2; i++)
#pragma unroll
    for (int j = 0; j < 2; j++) {
      const int n  = n0 + wn*32 + j*16 + lt;
      const float bv = bias[n];
      const int mb = m0 + wm*32 + i*16 + g*4;
#pragma unroll
      for (int r = 0; r < 4; r++) {
        const int mm = mb + r;
        if (EPI == 0) {
          const float val = (acc[i][j][r] + bv) * 0.17677669529663687f;
          const int bb = mm >> 9, s = mm & 511;
          const int d = n >> 8, ql = (n >> 3) & 31, hh = n & 7;
          const int tt = s*2 + d;
          ((ushort*)outp)[((size_t)(bb*8 + hh) * 1024 + tt) * 32 + ql] = f2bf(val);
        } else {
          ((float*)outp)[(size_t)mm * N + n] = acc[i][j][r] + bv;
        }
      }
    }
}

// ---------------------------------------------------------------------------
// Attention (split-n). R10 schedule verbatim (measured 50.5us): 8-buffer LDS
// ocs ring (DMA distance 4 steps), K/V prefetch distance 2 steps into named
// register sets, one pair (2 steps) per barrier. VMEM issue order per pair =
// [8 K/V, 2 DMA]: the compiler's wait for the current pair's K/V retires the
// previous pair's DMAs for free; pair-end vmcnt(10) retires exactly the DMAs
// needed one pair ahead, leaving K/V + younger DMAs in flight.
// Only launch-config change vs R10: NS=8 (grid 2048, nsteps=8).
// ---------------------------------------------------------------------------
__global__ __launch_bounds__(256) void attn_kernel(
    const ushort* __restrict__ qbf, const ushort* __restrict__ kbf,
    const ushort* __restrict__ vbf, const float* __restrict__ ocs,
    float* __restrict__ pacc, float* __restrict__ pl, int nsteps)
{
#if OCS_ASYNC
  __shared__ float obuf[8][1024];   // ring: 8 x [32 rows][8 slots][4 f32]
#endif
  const int tid  = threadIdx.x;
  const int lane = tid & 63;
  const int c  = blockIdx.x >> 8;
  const int bi = blockIdx.x & 255;
  const int wid = bi * 4 + (tid >> 6);
  const int b  = wid & 3;
  const int tt = (wid >> 2) & 31;
  const int h  = wid >> 7;
  const int t0 = tt * 32;
  const int lt = lane & 15, g = lane >> 4;
  const int n_start = c * nsteps * 32;

  const ushort* qp = qbf + (size_t)(b*8 + h) * (1024*32);
  const ushort* kp = kbf + (size_t)(b*8 + h) * (2048*32);
  const ushort* vp = vbf + (size_t)(b*8 + h) * (32*2048);
  const float*  op = ocs + (size_t)h * (1024*2048);

#define NSX(I) (((I) < nsteps) ? (n_start + (I)*32) : n_start)

  // ocs staging: thread -> row (tid>>3), slot (tid&7); source col is
  // inverse-swizzled so LDS slot s holds global cols 4*(s^(row&7))..+3.
  const int srow = tid >> 3;
  const int scol = 4 * ((tid & 7) ^ (srow & 7));
  const float* sb = op + (size_t)(t0 + srow) * 2048 + scol;
#if OCS_ASYNC
  const int ldsw = (tid & 192) * 16;   // per-wave LDS byte base (lane*16 added by HW)
#define SL_ISSUE(STEP) gl_lds16(sb + NSX(STEP), \
    (float*)((char*)obuf + (((STEP) & 7) << 12) + ldsw))
  // swizzled read offsets: sc0 cols 8g..8g+3 (slot 2g), sc1 cols 8g+4..8g+7
  // (slot 2g+1); row ts*16+lt.
  const int ro0 = lt * 128;            // ts=0 row byte offset
  const int ro1 = (16 + lt) * 128;     // ts=1
  const int c0x = ((2*g)     ^ (lt & 7)) * 16;   // sc0 slot bytes
  const int c1x = ((2*g + 1) ^ (lt & 7)) * 16;   // sc1 slot bytes
#define CO_READ(DST, STEP) do {                                               \
    const char* bb_ = (const char*)obuf + (((STEP) & 7) << 12);               \
    DST[0][0] = *(const f32x4*)(bb_ + ro0 + c0x);                             \
    DST[1][0] = *(const f32x4*)(bb_ + ro0 + c1x);                             \
    DST[0][1] = *(const f32x4*)(bb_ + ro1 + c0x);                             \
    DST[1][1] = *(const f32x4*)(bb_ + ro1 + c1x);                             \
  } while (0)
#define PAIR_SYNC() do {                                                      \
    __builtin_amdgcn_sched_barrier(0);                                        \
    asm volatile("s_waitcnt vmcnt(10)" ::: "memory");                         \
    __builtin_amdgcn_sched_barrier(0);                                        \
    __builtin_amdgcn_s_barrier();                                             \
  } while (0)
#else
  const float* opr0 = op + (size_t)(t0 + lt) * 2048;
  const float* opr1 = op + (size_t)(t0 + 16 + lt) * 2048;
#define SL_ISSUE(STEP)
#define CO_READ(DST, STEP) do {                                               \
    const int nn_ = NSX(STEP);                                                \
    DST[0][0] = *(const f32x4*)(opr0 + nn_ + 8*g);                            \
    DST[1][0] = *(const f32x4*)(opr0 + nn_ + 8*g + 4);                        \
    DST[0][1] = *(const f32x4*)(opr1 + nn_ + 8*g);                            \
    DST[1][1] = *(const f32x4*)(opr1 + nn_ + 8*g + 4);                        \
  } while (0)
#define PAIR_SYNC()
#endif

#define LD_KV(KD, VD, NN) do {                                                \
    KD[0] = *(const short8*)(kp + (size_t)((NN) + lt) * 32 + g*8);            \
    KD[1] = *(const short8*)(kp + (size_t)((NN) + 16 + lt) * 32 + g*8);       \
    VD[0] = *(const short8*)(vp + (size_t)lt * 2048 + (NN) + g*8);            \
    VD[1] = *(const short8*)(vp + (size_t)(16 + lt) * 2048 + (NN) + g*8);     \
  } while (0)

  short8 qf[2];
#pragma unroll
  for (int ts = 0; ts < 2; ts++)
    qf[ts] = *(const short8*)(qp + (t0 + ts*16 + lt)*32 + g*8);

  f32x4 acc[2][2] = {};
  float lsum[2] = {0.f, 0.f};
  const f32x4 fzero = {0.f, 0.f, 0.f, 0.f};

  // ts-block: exp + f2bf pack (P already in B-frag order via permuted K) + PV
#define TSB(SC0, SC1, CO0, CO1, VLO, VHI, LS, ACCA, ACCB) do {                \
    float p0 = __expf(SC0[0] - CO0[0]);                                       \
    float p1 = __expf(SC0[1] - CO0[1]);                                       \
    float p2 = __expf(SC0[2] - CO0[2]);                                       \
    float p3 = __expf(SC0[3] - CO0[3]);                                       \
    float p4 = __expf(SC1[0] - CO1[0]);                                       \
    float p5 = __expf(SC1[1] - CO1[1]);                                       \
    float p6 = __expf(SC1[2] - CO1[2]);                                       \
    float p7 = __expf(SC1[3] - CO1[3]);                                       \
    LS += ((p0+p1)+(p2+p3)) + ((p4+p5)+(p6+p7));                              \
    union { unsigned int u[4]; short8 s; } pf;                                \
    pf.u[0] = (unsigned int)f2bf(p0) | ((unsigned int)f2bf(p1) << 16);        \
    pf.u[1] = (unsigned int)f2bf(p2) | ((unsigned int)f2bf(p3) << 16);        \
    pf.u[2] = (unsigned int)f2bf(p4) | ((unsigned int)f2bf(p5) << 16);        \
    pf.u[3] = (unsigned int)f2bf(p6) | ((unsigned int)f2bf(p7) << 16);        \
    ACCA = __builtin_amdgcn_mfma_f32_16x16x32_bf16(VLO, pf.s, ACCA, 0, 0, 0); \
    ACCB = __builtin_amdgcn_mfma_f32_16x16x32_bf16(VHI, pf.s, ACCB, 0, 0, 0); \
  } while (0)

  // One pair = steps SA_, SA_+1. Consumes KV set (KC,VC); loads (KN,VN) for
  // steps SA_+2,SA_+3; stages ocs DMA for steps SA_+4,SA_+5.
#define PAIR(SA_, KC, VC, KN, VN) do {                                        \
    const int sA_ = (SA_);                                                    \
    LD_KV(KN[0], VN[0], NSX(sA_ + 2));                                        \
    LD_KV(KN[1], VN[1], NSX(sA_ + 3));                                        \
    SL_ISSUE(sA_ + 4);                                                        \
    SL_ISSUE(sA_ + 5);                                                        \
    __builtin_amdgcn_sched_barrier(0);                                        \
    f32x4 coA[2][2], coB[2][2];                                               \
    CO_READ(coA, sA_);                                                        \
    CO_READ(coB, sA_ + 1);                                                    \
    f32x4 scA0[2], scA1[2], scB0[2], scB1[2];                                 \
    _Pragma("unroll")                                                         \
    for (int ts = 0; ts < 2; ts++) {                                          \
      scA0[ts] = __builtin_amdgcn_mfma_f32_16x16x32_bf16(KC[0][0], qf[ts], fzero, 0, 0, 0); \
      scA1[ts] = __builtin_amdgcn_mfma_f32_16x16x32_bf16(KC[0][1], qf[ts], fzero, 0, 0, 0); \
      scB0[ts] = __builtin_amdgcn_mfma_f32_16x16x32_bf16(KC[1][0], qf[ts], fzero, 0, 0, 0); \
      scB1[ts] = __builtin_amdgcn_mfma_f32_16x16x32_bf16(KC[1][1], qf[ts], fzero, 0, 0, 0); \
    }                                                                         \
    TSB(scA0[0], scA1[0], coA[0][0], coA[1][0], VC[0][0], VC[0][1], lsum[0], acc[0][0], acc[0][1]); \
    TSB(scB0[0], scB1[0], coB[0][0], coB[1][0], VC[1][0], VC[1][1], lsum[0], acc[0][0], acc[0][1]); \
    TSB(scA0[1], scA1[1], coA[0][1], coA[1][1], VC[0][0], VC[0][1], lsum[1], acc[1][0], acc[1][1]); \
    TSB(scB0[1], scB1[1], coB[0][1], coB[1][1], VC[1][0], VC[1][1], lsum[1], acc[1][0], acc[1][1]); \
    PAIR_SYNC();                                                              \
  } while (0)

  // named K/V register sets: K*[pair-step][half], V*[pair-step][half]
  short8 KA[2][2], VA[2][2], KB[2][2], VB[2][2];

  // prologue: KV for steps 0,1 into set A; DMA steps 0..3 into ring 0..3.
  LD_KV(KA[0], VA[0], NSX(0));
  LD_KV(KA[1], VA[1], NSX(1));
#if OCS_ASYNC
  SL_ISSUE(0); SL_ISSUE(1); SL_ISSUE(2); SL_ISSUE(3);
  __builtin_amdgcn_sched_barrier(0);
  asm volatile("s_waitcnt vmcnt(2)" ::: "memory");   // bufs 0,1 ready; D2,D3 in flight
  __builtin_amdgcn_s_barrier();
#endif

  for (int s = 0; s < nsteps; s += 4) {
    PAIR(s,     KA, VA, KB, VB);   // steps s,s+1; load B for s+2,s+3
    PAIR(s + 2, KB, VB, KA, VA);   // steps s+2,s+3; load A for s+4,s+5
  }
#undef PAIR
#undef TSB
#undef LD_KV
#undef CO_READ
#undef SL_ISSUE
#undef PAIR_SYNC
#undef NSX

  // write partials: acc rows [((c*1024+wid)*4 + q)*256 + lane*4], q = ts*2+vs
  {
    float* pb = pacc + ((size_t)(c*1024 + wid) * 4) * 256 + lane * 4;
#pragma unroll
    for (int ts = 0; ts < 2; ts++)
#pragma unroll
      for (int vs = 0; vs < 2; vs++)
        *(f32x4*)(pb + (ts*2 + vs) * 256) = acc[ts][vs];
  }
  // reduce lsum over the 4 g-groups (columns are per-lt), store 32 per wid
#pragma unroll
  for (int ts = 0; ts < 2; ts++) {
    float L = lsum[ts];
    L += __shfl_xor(L, 16);
    L += __shfl_xor(L, 32);
    if (g == 0) pl[((size_t)(c*1024 + wid)) * 32 + ts*16 + lt] = L;
  }
}

// ---------------------------------------------------------------------------
// Combine partials across NS chunks, normalize, write vo[b*512+s][h*64+d*32+..]
// ---------------------------------------------------------------------------
__global__ __launch_bounds__(256) void combine_kernel(
    const float* __restrict__ pacc, const float* __restrict__ pl,
    float* __restrict__ vo, int NS)
{
  const int lane = threadIdx.x & 63;
  const int wid = blockIdx.x * 4 + (threadIdx.x >> 6);
  const int b  = wid & 3;
  const int tt = (wid >> 2) & 31;
  const int h  = wid >> 7;
  const int t0 = tt * 32;
  const int lt = lane & 15, g = lane >> 4;

  f32x4 acc[4] = {};
  float L[2] = {0.f, 0.f};
  for (int cc = 0; cc < NS; ++cc) {
    const float* pb = pacc + ((size_t)(cc*1024 + wid) * 4) * 256 + lane * 4;
#pragma unroll
    for (int q = 0; q < 4; q++) {
      f32x4 v = *(const f32x4*)(pb + q * 256);
#pragma unroll
      for (int r = 0; r < 4; r++) acc[q][r] += v[r];
    }
    L[0] += pl[((size_t)(cc*1024 + wid)) * 32 + lt];
    L[1] += pl[((size_t)(cc*1024 + wid)) * 32 + 16 + lt];
  }
#pragma unroll
  for (int ts = 0; ts < 2; ts++) {
    const float inv = 1.0f / L[ts];
    const int t = t0 + ts*16 + lt;
    const int s = t >> 1, d = t & 1;
    float* dst = vo + ((size_t)(b*512 + s) * 512) + h*64 + d*32;
#pragma unroll
    for (int vs = 0; vs < 2; vs++) {
      f32x4 o;
#pragma unroll
      for (int r = 0; r < 4; r++) o[r] = acc[ts*2 + vs][r] * inv;
      *(f32x4*)(dst + vs*16 + g*4) = o;
    }
  }
}

// ---------------------------------------------------------------------------
// LayerNorm over 512, one wave per row.
// ---------------------------------------------------------------------------
__global__ __launch_bounds__(256) void ln_kernel(
    const float* __restrict__ x_in, const float* __restrict__ gamma,
    const float* __restrict__ beta, float* __restrict__ x_out)
{
  const int row  = blockIdx.x * 4 + (threadIdx.x >> 6);
  const int lane = threadIdx.x & 63;
  const float* x = x_in + (size_t)row * 512 + lane * 8;
  f32x4 v0 = *(const f32x4*)x;
  f32x4 v1 = *(const f32x4*)(x + 4);
  float s = (v0[0]+v0[1]+v0[2]+v0[3]) + (v1[0]+v1[1]+v1[2]+v1[3]);
#pragma unroll
  for (int off = 1; off < 64; off <<= 1) s += __shfl_xor(s, off);
  const float mean = s * (1.0f/512.0f);
  float var = 0.f;
#pragma unroll
  for (int i = 0; i < 4; i++) {
    float d0 = v0[i]-mean, d1 = v1[i]-mean;
    var += d0*d0 + d1*d1;
  }
#pragma unroll
  for (int off = 1; off < 64; off <<= 1) var += __shfl_xor(var, off);
  const float rstd = rsqrtf(var * (1.0f/512.0f) + 1e-5f);
  const float* gp = gamma + lane*8;
  const float* bp = beta  + lane*8;
  f32x4 g0 = *(const f32x4*)gp, g1 = *(const f32x4*)(gp+4);
  f32x4 b0 = *(const f32x4*)bp, b1 = *(const f32x4*)(bp+4);
  f32x4 o0, o1;
#pragma unroll
  for (int i = 0; i < 4; i++) {
    o0[i] = (v0[i]-mean)*rstd*g0[i] + b0[i];
    o1[i] = (v1[i]-mean)*rstd*g1[i] + b1[i];
  }
  float* o = x_out + (size_t)row * 512 + lane * 8;
  *(f32x4*)o = o0;
  *(f32x4*)(o + 4) = o1;
}

// ---------------------------------------------------------------------------
extern "C" void kernel_launch(void* const* d_in, const int* in_sizes, int n_in,
                              void* d_out, int out_size, void* d_ws, size_t ws_size,
                              hipStream_t stream)
{
  const float* emb    = (const float*)d_in[0];
  const float* keys   = (const float*)d_in[1];
  const float* values = (const float*)d_in[2];
  const float* ocs    = (const float*)d_in[3];
  const float* Wq     = (const float*)d_in[4];
  const float* bq     = (const float*)d_in[5];
  const float* Wo     = (const float*)d_in[6];
  const float* bo     = (const float*)d_in[7];
  const float* gamma  = (const float*)d_in[8];
  const float* beta   = (const float*)d_in[9];

  char* ws = (char*)d_ws;
  ushort* qbf = (ushort*)(ws);                    // 2 MB  [b,h,t,ql] bf16
  ushort* kbf = (ushort*)(ws + (2u << 20));       // 4 MB  [b,h,n',ql] bf16 (permuted tiles)
  ushort* vbf = (ushort*)(ws + (6u << 20));       // 4 MB  [b,h,vl,n] bf16
  float*  vo  = (float*) (ws + (10u << 20));      // 4 MB  [m,512] f32
  const size_t pbase = (size_t)14u << 20;

  int NS;
  if      (ws_size >= ((size_t)48u << 20)) NS = 8;   // pacc 32MB + pl 1MB
  else if (ws_size >= ((size_t)31u << 20)) NS = 4;   // pacc 16MB + pl 0.5MB
  else if (ws_size >= ((size_t)23u << 20)) NS = 2;
  else                                     NS = 1;
  float* pacc = (float*)(ws + pbase);                            // NS*4MB
  float* pl   = (float*)(ws + pbase + (size_t)NS * (4u << 20));  // NS*128KB
  const int nsteps = 2048 / (NS * 32);

  prep_kv<<<dim3(256), dim3(256), 0, stream>>>(keys, values, kbf, vbf);
  gemm_nt<0><<<dim3(32, 8), dim3(256), 0, stream>>>(emb, Wq, bq, (void*)qbf, 2048, 512, 1024);
  attn_kernel<<<dim3(256 * NS), dim3(256), 0, stream>>>(qbf, kbf, vbf, ocs, pacc, pl, nsteps);
  combine_kernel<<<dim3(256), dim3(256), 0, stream>>>(pacc, pl, vo, NS);
  ln_kernel<<<dim3(512), dim3(256), 0, stream>>>(vo, gamma, beta, vo);
  gemm_nt<1><<<dim3(32, 16), dim3(256), 0, stream>>>(vo, Wo, bo, d_out, 2048, 1024, 512);
}

// Round 13
// 95.263 us; speedup vs baseline: 1.1550x; 1.1550x over previous
//
#include <hip/hip_runtime.h>
#include <hip/hip_bf16.h>

// Problem constants: B=4, S=512, N=2048, E=1024, QL=32, H=8, D=2, VL=32
// Inputs: 0 embeddings[4,512,1024] 1 keys[4,2048,256] 2 values[4,2048,256]
//         3 ocs[8,1024,2048] 4 Wq[512,1024] 5 bq[512] 6 Wo[1024,512] 7 bo[1024]
//         8 gamma[512] 9 beta[512]       all float32.  Output [4,512,1024] f32.

typedef short  short8 __attribute__((ext_vector_type(8)));
typedef float  f32x4  __attribute__((ext_vector_type(4)));

__device__ __forceinline__ ushort f2bf(float x) {
  union { float f; unsigned int u; } v; v.f = x;
  unsigned int r = v.u + 0x7fffu + ((v.u >> 16) & 1u);
  return (ushort)(r >> 16);
}

// hardware packed f32x2 -> bf16x2 (RNE), 1 instr. Used ONLY where the
// consumer is a DS/shuffle/store op (never directly feeding MFMA).
__device__ __forceinline__ unsigned int cvtpk(float a, float b) {
  unsigned int r;
  asm("v_cvt_pk_bf16_f32 %0, %1, %2" : "=v"(r) : "v"(a), "v"(b));
  return r;
}
__device__ __forceinline__ short8 cvt8(f32x4 a, f32x4 b) {
  union { unsigned int u[4]; short8 s; } r;
  r.u[0] = cvtpk(a[0], a[1]);
  r.u[1] = cvtpk(a[2], a[3]);
  r.u[2] = cvtpk(b[0], b[1]);
  r.u[3] = cvtpk(b[2], b[3]);
  return r.s;
}

#if __has_builtin(__builtin_amdgcn_global_load_lds)
#define OCS_ASYNC 1
__device__ __forceinline__ void gl_lds16(const float* g, float* l) {
  __builtin_amdgcn_global_load_lds(
      (const __attribute__((address_space(1))) unsigned int*)g,
      (__attribute__((address_space(3))) unsigned int*)l, 16, 0, 0);
}
#else
#define OCS_ASYNC 0
#endif

// ---------------------------------------------------------------------------
// prep: keys[b,n,ql*8+h] -> kbf[b,h,n',ql] (bf16) where within each 32-row
// tile, position p = 16s+4gg+r holds source row sigma(p) = 8gg+4s+r. This
// makes the QK^T MFMA output land directly in the K=32 PV B-fragment order
// (lane g holds n = 8g+0..3 from sc0 and 8g+4..7 from sc1) -- no shuffles.
// values[b,n,vl*8+h] -> vbf[b,h,vl,n] (unpermuted).
// ---------------------------------------------------------------------------
__global__ __launch_bounds__(256) void prep_kv(
    const float* __restrict__ keys, const float* __restrict__ values,
    ushort* __restrict__ kbf, ushort* __restrict__ vbf)
{
  __shared__ ushort T[32][264];
  const int bi = blockIdx.x;            // 0..255
  const int b  = bi >> 6;
  const int n0 = (bi & 63) * 32;
  const int t  = threadIdx.x;
  const int nr = t >> 3;                // 0..31
  const int c0 = (t & 7) * 32;          // 0..224

  {
    const float* src = keys + ((size_t)b*2048 + n0 + nr)*256 + c0;
#pragma unroll
    for (int j = 0; j < 32; j += 8) {
      f32x4 x0 = *(const f32x4*)(src + j);
      f32x4 x1 = *(const f32x4*)(src + j + 4);
      *(short8*)&T[nr][c0 + j] = cvt8(x0, x1);
    }
  }
  __syncthreads();
  {
    const int h = t >> 5, nn = t & 31;
    // inverse permutation: source row nn -> tile position pp
    const int pp = 16*((nn >> 2) & 1) + 4*(nn >> 3) + (nn & 3);
    ushort* dst = kbf + (((size_t)(b*8 + h) * 2048) + n0 + pp) * 32;
#pragma unroll
    for (int j = 0; j < 4; j++) {
      short8 w;
#pragma unroll
      for (int i = 0; i < 8; i++) w[i] = (short)T[nn][(j*8 + i)*8 + h];
      *(short8*)(dst + j*8) = w;
    }
  }
  __syncthreads();
  {
    const float* src = values + ((size_t)b*2048 + n0 + nr)*256 + c0;
#pragma unroll
    for (int j = 0; j < 32; j += 8) {
      f32x4 x0 = *(const f32x4*)(src + j);
      f32x4 x1 = *(const f32x4*)(src + j + 4);
      *(short8*)&T[nr][c0 + j] = cvt8(x0, x1);
    }
  }
  __syncthreads();
  {
    const int c = t, h = c & 7, vl = c >> 3;
    ushort* dst = vbf + (((size_t)(b*8 + h) * 32) + vl) * 2048 + n0;
#pragma unroll
    for (int j = 0; j < 4; j++) {
      short8 w;
#pragma unroll
      for (int i = 0; i < 8; i++) w[i] = (short)T[j*8 + i][c];
      *(short8*)(dst + j*8) = w;
    }
  }
}

// ---------------------------------------------------------------------------
// GEMM (NT): out[m,n] = sum_k A[m,k]*B[n,k] + bias[n]. 64x64 tile, 4 waves.
// EPI=0: scatter-store bf16*(1/sqrt(32)) into qbf[b,h,t,ql]; EPI=1: f32 out.
// ---------------------------------------------------------------------------
template<int EPI>
__global__ __launch_bounds__(256) void gemm_nt(
    const float* __restrict__ A, const float* __restrict__ Bm,
    const float* __restrict__ bias, void* __restrict__ outp,
    int M, int N, int K)
{
  __shared__ ushort As[64][32];
  __shared__ ushort Bs[64][32];
  const int tid = threadIdx.x;
  const int m0 = blockIdx.x * 64;
  const int n0 = blockIdx.y * 64;
  const int lane = tid & 63;
  const int wid  = tid >> 6;
  const int wm = wid >> 1, wn = wid & 1;
  const int lt = lane & 15, g = lane >> 4;
  const int lrow = tid >> 2;      // 0..63
  const int lseg = tid & 3;       // 0..3 (8 floats each)
  const int slot_w = lseg ^ ((lrow & 3) ^ ((lrow >> 2) & 3));

  f32x4 acc[2][2] = {};

  for (int k0 = 0; k0 < K; k0 += 32) {
    {
      const float* sa = A + (size_t)(m0 + lrow) * K + k0 + lseg * 8;
      f32x4 a0 = *(const f32x4*)sa;
      f32x4 a1 = *(const f32x4*)(sa + 4);
      *(short8*)&As[lrow][slot_w * 8] = cvt8(a0, a1);
      const float* sb = Bm + (size_t)(n0 + lrow) * K + k0 + lseg * 8;
      f32x4 b0 = *(const f32x4*)sb;
      f32x4 b1 = *(const f32x4*)(sb + 4);
      *(short8*)&Bs[lrow][slot_w * 8] = cvt8(b0, b1);
    }
    __syncthreads();
    short8 af[2], bfr[2];
#pragma unroll
    for (int ss = 0; ss < 2; ss++) {
      const int ra = wm*32 + ss*16 + lt;
      af[ss]  = *(const short8*)&As[ra][(g ^ ((ra & 3) ^ ((ra >> 2) & 3))) * 8];
      const int rb = wn*32 + ss*16 + lt;
      bfr[ss] = *(const short8*)&Bs[rb][(g ^ ((rb & 3) ^ ((rb >> 2) & 3))) * 8];
    }
#pragma unroll
    for (int i = 0; i < 2; i++)
#pragma unroll
      for (int j = 0; j < 2; j++)
        acc[i][j] = __builtin_amdgcn_mfma_f32_16x16x32_bf16(af[i], bfr[j], acc[i][j], 0, 0, 0);
    __syncthreads();
  }

#pragma unroll
  for (int i = 0; i < 2; i++)
#pragma unroll
    for (int j = 0; j < 2; j++) {
      const int n  = n0 + wn*32 + j*16 + lt;
      const float bv = bias[n];
      const int mb = m0 + wm*32 + i*16 + g*4;
#pragma unroll
      for (int r = 0; r < 4; r++) {
        const int mm = mb + r;
        if (EPI == 0) {
          const float val = (acc[i][j][r] + bv) * 0.17677669529663687f;
          const int bb = mm >> 9, s = mm & 511;
          const int d = n >> 8, ql = (n >> 3) & 31, hh = n & 7;
          const int tt = s*2 + d;
          ((ushort*)outp)[((size_t)(bb*8 + hh) * 1024 + tt) * 32 + ql] = f2bf(val);
        } else {
          ((float*)outp)[(size_t)mm * N + n] = acc[i][j][r] + bv;
        }
      }
    }
}

// ---------------------------------------------------------------------------
// Attention (split-n), t-PAIR per wave: each wave owns TWO t-tiles (t0,
// t0+32) sharing the same K/V registers (halves K/V L2 traffic, doubles
// per-pair independent chains). Schedule topology = R10/R12 (proven):
// 8-buffer LDS ocs ring (now 8KB/buf = 2 tiles), DMA distance 4 steps,
// K/V prefetch distance 2 steps (named sets), KV-first issue per pair +
// vmcnt(12) (keeps 8 K/V + 4 DMA; forces pair-old DMAs exactly one pair
// before their consumer). Math per tile byte-identical to R12.
// Block = 4 waves = 4 batches of one (h, ttp, c). Grid = 128*NS.
// ---------------------------------------------------------------------------
__global__ __launch_bounds__(256) void attn_kernel(
    const ushort* __restrict__ qbf, const ushort* __restrict__ kbf,
    const ushort* __restrict__ vbf, const float* __restrict__ ocs,
    float* __restrict__ pacc, float* __restrict__ pl, int nsteps)
{
#if OCS_ASYNC
  __shared__ float obuf[8][2048];   // ring: 8 x [2 tiles][32 rows][8 slots][4 f32]
#endif
  const int tid  = threadIdx.x;
  const int lane = tid & 63;
  const int id = blockIdx.x;
  const int h   = id & 7;
  const int ttp = (id >> 3) & 15;
  const int c   = id >> 7;
  const int b  = tid >> 6;
  const int wid0 = ((h << 5) + 2*ttp) * 4 + b;   // tile0's wid; tile1 = wid0+4
  const int t0 = ttp * 64;
  const int lt = lane & 15, g = lane >> 4;
  const int n_start = c * nsteps * 32;

  const ushort* qp = qbf + (size_t)(b*8 + h) * (1024*32);
  const ushort* kp = kbf + (size_t)(b*8 + h) * (2048*32);
  const ushort* vp = vbf + (size_t)(b*8 + h) * (32*2048);
  const float*  op = ocs + (size_t)h * (1024*2048);

#define NSX(I) (((I) < nsteps) ? (n_start + (I)*32) : n_start)

  // ocs staging: thread -> row (tid>>3), slot (tid&7); source col is
  // inverse-swizzled so LDS slot s holds global cols 4*(s^(row&7))..+3.
  const int srow = tid >> 3;
  const int scol = 4 * ((tid & 7) ^ (srow & 7));
  const float* sb0 = op + (size_t)(t0 + srow) * 2048 + scol;
  const float* sb1 = op + (size_t)(t0 + 32 + srow) * 2048 + scol;
#if OCS_ASYNC
  const int ldsw = (tid & 192) * 16;   // per-wave LDS byte base (lane*16 added by HW)
#define SL_ISSUE(STEP) do {                                                   \
    gl_lds16(sb0 + NSX(STEP), (float*)((char*)obuf + (((STEP) & 7) << 13) + ldsw));        \
    gl_lds16(sb1 + NSX(STEP), (float*)((char*)obuf + (((STEP) & 7) << 13) + 4096 + ldsw)); \
  } while (0)
  // swizzled read offsets: sc0 cols 8g..8g+3 (slot 2g), sc1 cols 8g+4..8g+7
  // (slot 2g+1); row ts*16+lt.
  const int ro0 = lt * 128;            // ts=0 row byte offset
  const int ro1 = (16 + lt) * 128;     // ts=1
  const int c0x = ((2*g)     ^ (lt & 7)) * 16;   // sc0 slot bytes
  const int c1x = ((2*g + 1) ^ (lt & 7)) * 16;   // sc1 slot bytes
#define CO_READ(DST, TILE, STEP) do {                                         \
    const char* bb_ = (const char*)obuf + (((STEP) & 7) << 13) + ((TILE) << 12); \
    DST[0][0] = *(const f32x4*)(bb_ + ro0 + c0x);                             \
    DST[1][0] = *(const f32x4*)(bb_ + ro0 + c1x);                             \
    DST[0][1] = *(const f32x4*)(bb_ + ro1 + c0x);                             \
    DST[1][1] = *(const f32x4*)(bb_ + ro1 + c1x);                             \
  } while (0)
#define PAIR_SYNC() do {                                                      \
    __builtin_amdgcn_sched_barrier(0);                                        \
    asm volatile("s_waitcnt vmcnt(12)" ::: "memory");                         \
    __builtin_amdgcn_sched_barrier(0);                                        \
    __builtin_amdgcn_s_barrier();                                             \
  } while (0)
#else
#define SL_ISSUE(STEP)
#define CO_READ(DST, TILE, STEP) do {                                         \
    const int nn_ = NSX(STEP);                                                \
    const float* r0_ = op + (size_t)(t0 + (TILE)*32 + lt) * 2048 + nn_;       \
    const float* r1_ = op + (size_t)(t0 + (TILE)*32 + 16 + lt) * 2048 + nn_;  \
    DST[0][0] = *(const f32x4*)(r0_ + 8*g);                                   \
    DST[1][0] = *(const f32x4*)(r0_ + 8*g + 4);                               \
    DST[0][1] = *(const f32x4*)(r1_ + 8*g);                                   \
    DST[1][1] = *(const f32x4*)(r1_ + 8*g + 4);                               \
  } while (0)
#define PAIR_SYNC()
#endif

#define LD_KV(KD, VD, NN) do {                                                \
    KD[0] = *(const short8*)(kp + (size_t)((NN) + lt) * 32 + g*8);            \
    KD[1] = *(const short8*)(kp + (size_t)((NN) + 16 + lt) * 32 + g*8);       \
    VD[0] = *(const short8*)(vp + (size_t)lt * 2048 + (NN) + g*8);            \
    VD[1] = *(const short8*)(vp + (size_t)(16 + lt) * 2048 + (NN) + g*8);     \
  } while (0)

  short8 qf0[2], qf1[2];
#pragma unroll
  for (int ts = 0; ts < 2; ts++) {
    qf0[ts] = *(const short8*)(qp + (t0 + ts*16 + lt)*32 + g*8);
    qf1[ts] = *(const short8*)(qp + (t0 + 32 + ts*16 + lt)*32 + g*8);
  }

  f32x4 acc0[2][2] = {}, acc1[2][2] = {};
  float lsum0[2] = {0.f, 0.f}, lsum1[2] = {0.f, 0.f};
  const f32x4 fzero = {0.f, 0.f, 0.f, 0.f};

  // ts-block: exp + f2bf pack (P already in B-frag order via permuted K) + PV
#define TSB(SC0, SC1, CO0, CO1, VLO, VHI, LS, ACCA, ACCB) do {                \
    float p0 = __expf(SC0[0] - CO0[0]);                                       \
    float p1 = __expf(SC0[1] - CO0[1]);                                       \
    float p2 = __expf(SC0[2] - CO0[2]);                                       \
    float p3 = __expf(SC0[3] - CO0[3]);                                       \
    float p4 = __expf(SC1[0] - CO1[0]);                                       \
    float p5 = __expf(SC1[1] - CO1[1]);                                       \
    float p6 = __expf(SC1[2] - CO1[2]);                                       \
    float p7 = __expf(SC1[3] - CO1[3]);                                       \
    LS += ((p0+p1)+(p2+p3)) + ((p4+p5)+(p6+p7));                              \
    union { unsigned int u[4]; short8 s; } pf;                                \
    pf.u[0] = (unsigned int)f2bf(p0) | ((unsigned int)f2bf(p1) << 16);        \
    pf.u[1] = (unsigned int)f2bf(p2) | ((unsigned int)f2bf(p3) << 16);        \
    pf.u[2] = (unsigned int)f2bf(p4) | ((unsigned int)f2bf(p5) << 16);        \
    pf.u[3] = (unsigned int)f2bf(p6) | ((unsigned int)f2bf(p7) << 16);        \
    ACCA = __builtin_amdgcn_mfma_f32_16x16x32_bf16(VLO, pf.s, ACCA, 0, 0, 0); \
    ACCB = __builtin_amdgcn_mfma_f32_16x16x32_bf16(VHI, pf.s, ACCB, 0, 0, 0); \
  } while (0)

  // One step x one tile: 4 QK MFMAs, LDS co read, 2 TSBs (8 MFMA total).
#define STEPTILE(KC_, VC_, QFA, QFB, TILE, STEP, ACC, LS) do {                \
    f32x4 s0a = __builtin_amdgcn_mfma_f32_16x16x32_bf16(KC_[0], QFA, fzero, 0, 0, 0); \
    f32x4 s1a = __builtin_amdgcn_mfma_f32_16x16x32_bf16(KC_[1], QFA, fzero, 0, 0, 0); \
    f32x4 s0b = __builtin_amdgcn_mfma_f32_16x16x32_bf16(KC_[0], QFB, fzero, 0, 0, 0); \
    f32x4 s1b = __builtin_amdgcn_mfma_f32_16x16x32_bf16(KC_[1], QFB, fzero, 0, 0, 0); \
    f32x4 co[2][2];                                                           \
    CO_READ(co, TILE, STEP);                                                  \
    TSB(s0a, s1a, co[0][0], co[1][0], VC_[0], VC_[1], LS[0], ACC[0][0], ACC[0][1]); \
    TSB(s0b, s1b, co[0][1], co[1][1], VC_[0], VC_[1], LS[1], ACC[1][0], ACC[1][1]); \
  } while (0)

  // One pair = steps SA_, SA_+1 for BOTH tiles. Issues [8 K/V (steps +2,+3)]
  // then [4 DMA (steps +4,+5)]; pair-end vmcnt(12) keeps exactly those 12.
#define PAIR(SA_, KC, VC, KN, VN) do {                                        \
    const int sA_ = (SA_);                                                    \
    LD_KV(KN[0], VN[0], NSX(sA_ + 2));                                        \
    LD_KV(KN[1], VN[1], NSX(sA_ + 3));                                        \
    SL_ISSUE(sA_ + 4);                                                        \
    SL_ISSUE(sA_ + 5);                                                        \
    __builtin_amdgcn_sched_barrier(0);                                        \
    STEPTILE(KC[0], VC[0], qf0[0], qf0[1], 0, sA_,     acc0, lsum0);          \
    STEPTILE(KC[0], VC[0], qf1[0], qf1[1], 1, sA_,     acc1, lsum1);          \
    STEPTILE(KC[1], VC[1], qf0[0], qf0[1], 0, sA_ + 1, acc0, lsum0);          \
    STEPTILE(KC[1], VC[1], qf1[0], qf1[1], 1, sA_ + 1, acc1, lsum1);          \
    PAIR_SYNC();                                                              \
  } while (0)

  // named K/V register sets: K*[pair-step][half], V*[pair-step][half]
  short8 KA[2][2], VA[2][2], KB[2][2], VB[2][2];

  // prologue: DMA-FIRST (steps 0..3), then KV for steps 0,1. vmcnt(12) keeps
  // [8 KV + DMA steps 2,3], forcing bufs 0,1 complete.
#if OCS_ASYNC
  SL_ISSUE(0); SL_ISSUE(1); SL_ISSUE(2); SL_ISSUE(3);
  __builtin_amdgcn_sched_barrier(0);
#endif
  LD_KV(KA[0], VA[0], NSX(0));
  LD_KV(KA[1], VA[1], NSX(1));
#if OCS_ASYNC
  __builtin_amdgcn_sched_barrier(0);
  asm volatile("s_waitcnt vmcnt(12)" ::: "memory");
  __builtin_amdgcn_s_barrier();
#endif

  for (int s = 0; s < nsteps; s += 4) {
    PAIR(s,     KA, VA, KB, VB);   // steps s,s+1; load B for s+2,s+3
    PAIR(s + 2, KB, VB, KA, VA);   // steps s+2,s+3; load A for s+4,s+5
  }
#undef PAIR
#undef STEPTILE
#undef TSB
#undef LD_KV
#undef CO_READ
#undef SL_ISSUE
#undef PAIR_SYNC
#undef NSX

  // write partials for both tiles: rows [((c*1024+wid)*4 + q)*256 + lane*4]
  {
    float* pb0 = pacc + ((size_t)(c*1024 + wid0) * 4) * 256 + lane * 4;
    *(f32x4*)(pb0 + 0*256) = acc0[0][0];
    *(f32x4*)(pb0 + 1*256) = acc0[0][1];
    *(f32x4*)(pb0 + 2*256) = acc0[1][0];
    *(f32x4*)(pb0 + 3*256) = acc0[1][1];
    float* pb1 = pacc + ((size_t)(c*1024 + wid0 + 4) * 4) * 256 + lane * 4;
    *(f32x4*)(pb1 + 0*256) = acc1[0][0];
    *(f32x4*)(pb1 + 1*256) = acc1[0][1];
    *(f32x4*)(pb1 + 2*256) = acc1[1][0];
    *(f32x4*)(pb1 + 3*256) = acc1[1][1];
  }
  // reduce lsum over the 4 g-groups, store 32 per wid (both tiles)
#pragma unroll
  for (int ts = 0; ts < 2; ts++) {
    float L0 = lsum0[ts], L1 = lsum1[ts];
    L0 += __shfl_xor(L0, 16);  L0 += __shfl_xor(L0, 32);
    L1 += __shfl_xor(L1, 16);  L1 += __shfl_xor(L1, 32);
    if (g == 0) {
      pl[((size_t)(c*1024 + wid0)) * 32 + ts*16 + lt]     = L0;
      pl[((size_t)(c*1024 + wid0 + 4)) * 32 + ts*16 + lt] = L1;
    }
  }
}

// ---------------------------------------------------------------------------
// Combine partials across NS chunks, normalize, write vo[b*512+s][h*64+d*32+..]
// ---------------------------------------------------------------------------
__global__ __launch_bounds__(256) void combine_kernel(
    const float* __restrict__ pacc, const float* __restrict__ pl,
    float* __restrict__ vo, int NS)
{
  const int lane = threadIdx.x & 63;
  const int wid = blockIdx.x * 4 + (threadIdx.x >> 6);
  const int b  = wid & 3;
  const int tt = (wid >> 2) & 31;
  const int h  = wid >> 7;
  const int t0 = tt * 32;
  const int lt = lane & 15, g = lane >> 4;

  f32x4 acc[4] = {};
  float L[2] = {0.f, 0.f};
  for (int cc = 0; cc < NS; ++cc) {
    const float* pb = pacc + ((size_t)(cc*1024 + wid) * 4) * 256 + lane * 4;
#pragma unroll
    for (int q = 0; q < 4; q++) {
      f32x4 v = *(const f32x4*)(pb + q * 256);
#pragma unroll
      for (int r = 0; r < 4; r++) acc[q][r] += v[r];
    }
    L[0] += pl[((size_t)(cc*1024 + wid)) * 32 + lt];
    L[1] += pl[((size_t)(cc*1024 + wid)) * 32 + 16 + lt];
  }
#pragma unroll
  for (int ts = 0; ts < 2; ts++) {
    const float inv = 1.0f / L[ts];
    const int t = t0 + ts*16 + lt;
    const int s = t >> 1, d = t & 1;
    float* dst = vo + ((size_t)(b*512 + s) * 512) + h*64 + d*32;
#pragma unroll
    for (int vs = 0; vs < 2; vs++) {
      f32x4 o;
#pragma unroll
      for (int r = 0; r < 4; r++) o[r] = acc[ts*2 + vs][r] * inv;
      *(f32x4*)(dst + vs*16 + g*4) = o;
    }
  }
}

// ---------------------------------------------------------------------------
// LayerNorm over 512, one wave per row.
// ---------------------------------------------------------------------------
__global__ __launch_bounds__(256) void ln_kernel(
    const float* __restrict__ x_in, const float* __restrict__ gamma,
    const float* __restrict__ beta, float* __restrict__ x_out)
{
  const int row  = blockIdx.x * 4 + (threadIdx.x >> 6);
  const int lane = threadIdx.x & 63;
  const float* x = x_in + (size_t)row * 512 + lane * 8;
  f32x4 v0 = *(const f32x4*)x;
  f32x4 v1 = *(const f32x4*)(x + 4);
  float s = (v0[0]+v0[1]+v0[2]+v0[3]) + (v1[0]+v1[1]+v1[2]+v1[3]);
#pragma unroll
  for (int off = 1; off < 64; off <<= 1) s += __shfl_xor(s, off);
  const float mean = s * (1.0f/512.0f);
  float var = 0.f;
#pragma unroll
  for (int i = 0; i < 4; i++) {
    float d0 = v0[i]-mean, d1 = v1[i]-mean;
    var += d0*d0 + d1*d1;
  }
#pragma unroll
  for (int off = 1; off < 64; off <<= 1) var += __shfl_xor(var, off);
  const float rstd = rsqrtf(var * (1.0f/512.0f) + 1e-5f);
  const float* gp = gamma + lane*8;
  const float* bp = beta  + lane*8;
  f32x4 g0 = *(const f32x4*)gp, g1 = *(const f32x4*)(gp+4);
  f32x4 b0 = *(const f32x4*)bp, b1 = *(const f32x4*)(bp+4);
  f32x4 o0, o1;
#pragma unroll
  for (int i = 0; i < 4; i++) {
    o0[i] = (v0[i]-mean)*rstd*g0[i] + b0[i];
    o1[i] = (v1[i]-mean)*rstd*g1[i] + b1[i];
  }
  float* o = x_out + (size_t)row * 512 + lane * 8;
  *(f32x4*)o = o0;
  *(f32x4*)(o + 4) = o1;
}

// ---------------------------------------------------------------------------
extern "C" void kernel_launch(void* const* d_in, const int* in_sizes, int n_in,
                              void* d_out, int out_size, void* d_ws, size_t ws_size,
                              hipStream_t stream)
{
  const float* emb    = (const float*)d_in[0];
  const float* keys   = (const float*)d_in[1];
  const float* values = (const float*)d_in[2];
  const float* ocs    = (const float*)d_in[3];
  const float* Wq     = (const float*)d_in[4];
  const float* bq     = (const float*)d_in[5];
  const float* Wo     = (const float*)d_in[6];
  const float* bo     = (const float*)d_in[7];
  const float* gamma  = (const float*)d_in[8];
  const float* beta   = (const float*)d_in[9];

  char* ws = (char*)d_ws;
  ushort* qbf = (ushort*)(ws);                    // 2 MB  [b,h,t,ql] bf16
  ushort* kbf = (ushort*)(ws + (2u << 20));       // 4 MB  [b,h,n',ql] bf16 (permuted tiles)
  ushort* vbf = (ushort*)(ws + (6u << 20));       // 4 MB  [b,h,vl,n] bf16
  float*  vo  = (float*) (ws + (10u << 20));      // 4 MB  [m,512] f32
  const size_t pbase = (size_t)14u << 20;

  int NS;
  if      (ws_size >= ((size_t)48u << 20)) NS = 8;   // pacc 32MB + pl 1MB
  else if (ws_size >= ((size_t)31u << 20)) NS = 4;   // pacc 16MB + pl 0.5MB
  else if (ws_size >= ((size_t)23u << 20)) NS = 2;
  else                                     NS = 1;
  float* pacc = (float*)(ws + pbase);                            // NS*4MB
  float* pl   = (float*)(ws + pbase + (size_t)NS * (4u << 20));  // NS*128KB
  const int nsteps = 2048 / (NS * 32);

  prep_kv<<<dim3(256), dim3(256), 0, stream>>>(keys, values, kbf, vbf);
  gemm_nt<0><<<dim3(32, 8), dim3(256), 0, stream>>>(emb, Wq, bq, (void*)qbf, 2048, 512, 1024);
  attn_kernel<<<dim3(128 * NS), dim3(256), 0, stream>>>(qbf, kbf, vbf, ocs, pacc, pl, nsteps);
  combine_kernel<<<dim3(256), dim3(256), 0, stream>>>(pacc, pl, vo, NS);
  ln_kernel<<<dim3(512), dim3(256), 0, stream>>>(vo, gamma, beta, vo);
  gemm_nt<1><<<dim3(32, 16), dim3(256), 0, stream>>>(vo, Wo, bo, d_out, 2048, 1024, 512);
}

// Round 14
// 93.625 us; speedup vs baseline: 1.1752x; 1.0175x over previous
//
#include <hip/hip_runtime.h>
#include <hip/hip_bf16.h>

// Problem constants: B=4, S=512, N=2048, E=1024, QL=32, H=8, D=2, VL=32
// Inputs: 0 embeddings[4,512,1024] 1 keys[4,2048,256] 2 values[4,2048,256]
//         3 ocs[8,1024,2048] 4 Wq[512,1024] 5 bq[512] 6 Wo[1024,512] 7 bo[1024]
//         8 gamma[512] 9 beta[512]       all float32.  Output [4,512,1024] f32.

typedef short  short8 __attribute__((ext_vector_type(8)));
typedef float  f32x4  __attribute__((ext_vector_type(4)));

__device__ __forceinline__ ushort f2bf(float x) {
  union { float f; unsigned int u; } v; v.f = x;
  unsigned int r = v.u + 0x7fffu + ((v.u >> 16) & 1u);
  return (ushort)(r >> 16);
}

// hardware packed f32x2 -> bf16x2 (RNE), 1 instr. Used ONLY where the
// consumer is a DS/shuffle/store op (never directly feeding MFMA).
__device__ __forceinline__ unsigned int cvtpk(float a, float b) {
  unsigned int r;
  asm("v_cvt_pk_bf16_f32 %0, %1, %2" : "=v"(r) : "v"(a), "v"(b));
  return r;
}
__device__ __forceinline__ short8 cvt8(f32x4 a, f32x4 b) {
  union { unsigned int u[4]; short8 s; } r;
  r.u[0] = cvtpk(a[0], a[1]);
  r.u[1] = cvtpk(a[2], a[3]);
  r.u[2] = cvtpk(b[0], b[1]);
  r.u[3] = cvtpk(b[2], b[3]);
  return r.s;
}

#if __has_builtin(__builtin_amdgcn_global_load_lds)
#define OCS_ASYNC 1
__device__ __forceinline__ void gl_lds16(const float* g, float* l) {
  __builtin_amdgcn_global_load_lds(
      (const __attribute__((address_space(1))) unsigned int*)g,
      (__attribute__((address_space(3))) unsigned int*)l, 16, 0, 0);
}
#else
#define OCS_ASYNC 0
#endif

// ---------------------------------------------------------------------------
// prep: keys[b,n,ql*8+h] -> kbf[b,h,n',ql] (bf16) where within each 32-row
// tile, position p = 16s+4gg+r holds source row sigma(p) = 8gg+4s+r. This
// makes the QK^T MFMA output land directly in the K=32 PV B-fragment order
// (lane g holds n = 8g+0..3 from sc0 and 8g+4..7 from sc1) -- no shuffles.
// values[b,n,vl*8+h] -> vbf[b,h,vl,n] (unpermuted).
// ---------------------------------------------------------------------------
__global__ __launch_bounds__(256) void prep_kv(
    const float* __restrict__ keys, const float* __restrict__ values,
    ushort* __restrict__ kbf, ushort* __restrict__ vbf)
{
  __shared__ ushort T[32][264];
  const int bi = blockIdx.x;            // 0..255
  const int b  = bi >> 6;
  const int n0 = (bi & 63) * 32;
  const int t  = threadIdx.x;
  const int nr = t >> 3;                // 0..31
  const int c0 = (t & 7) * 32;          // 0..224

  {
    const float* src = keys + ((size_t)b*2048 + n0 + nr)*256 + c0;
#pragma unroll
    for (int j = 0; j < 32; j += 8) {
      f32x4 x0 = *(const f32x4*)(src + j);
      f32x4 x1 = *(const f32x4*)(src + j + 4);
      *(short8*)&T[nr][c0 + j] = cvt8(x0, x1);
    }
  }
  __syncthreads();
  {
    const int h = t >> 5, nn = t & 31;
    // inverse permutation: source row nn -> tile position pp
    const int pp = 16*((nn >> 2) & 1) + 4*(nn >> 3) + (nn & 3);
    ushort* dst = kbf + (((size_t)(b*8 + h) * 2048) + n0 + pp) * 32;
#pragma unroll
    for (int j = 0; j < 4; j++) {
      short8 w;
#pragma unroll
      for (int i = 0; i < 8; i++) w[i] = (short)T[nn][(j*8 + i)*8 + h];
      *(short8*)(dst + j*8) = w;
    }
  }
  __syncthreads();
  {
    const float* src = values + ((size_t)b*2048 + n0 + nr)*256 + c0;
#pragma unroll
    for (int j = 0; j < 32; j += 8) {
      f32x4 x0 = *(const f32x4*)(src + j);
      f32x4 x1 = *(const f32x4*)(src + j + 4);
      *(short8*)&T[nr][c0 + j] = cvt8(x0, x1);
    }
  }
  __syncthreads();
  {
    const int c = t, h = c & 7, vl = c >> 3;
    ushort* dst = vbf + (((size_t)(b*8 + h) * 32) + vl) * 2048 + n0;
#pragma unroll
    for (int j = 0; j < 4; j++) {
      short8 w;
#pragma unroll
      for (int i = 0; i < 8; i++) w[i] = (short)T[j*8 + i][c];
      *(short8*)(dst + j*8) = w;
    }
  }
}

// ---------------------------------------------------------------------------
// GEMM (NT): out[m,n] = sum_k A[m,k]*B[n,k] + bias[n]. 64x64 tile, 4 waves.
// EPI=0: scatter-store bf16*(1/sqrt(32)) into qbf[b,h,t,ql]; EPI=1: f32 out.
// ---------------------------------------------------------------------------
template<int EPI>
__global__ __launch_bounds__(256) void gemm_nt(
    const float* __restrict__ A, const float* __restrict__ Bm,
    const float* __restrict__ bias, void* __restrict__ outp,
    int M, int N, int K)
{
  __shared__ ushort As[64][32];
  __shared__ ushort Bs[64][32];
  const int tid = threadIdx.x;
  const int m0 = blockIdx.x * 64;
  const int n0 = blockIdx.y * 64;
  const int lane = tid & 63;
  const int wid  = tid >> 6;
  const int wm = wid >> 1, wn = wid & 1;
  const int lt = lane & 15, g = lane >> 4;
  const int lrow = tid >> 2;      // 0..63
  const int lseg = tid & 3;       // 0..3 (8 floats each)
  const int slot_w = lseg ^ ((lrow & 3) ^ ((lrow >> 2) & 3));

  f32x4 acc[2][2] = {};

  for (int k0 = 0; k0 < K; k0 += 32) {
    {
      const float* sa = A + (size_t)(m0 + lrow) * K + k0 + lseg * 8;
      f32x4 a0 = *(const f32x4*)sa;
      f32x4 a1 = *(const f32x4*)(sa + 4);
      *(short8*)&As[lrow][slot_w * 8] = cvt8(a0, a1);
      const float* sb = Bm + (size_t)(n0 + lrow) * K + k0 + lseg * 8;
      f32x4 b0 = *(const f32x4*)sb;
      f32x4 b1 = *(const f32x4*)(sb + 4);
      *(short8*)&Bs[lrow][slot_w * 8] = cvt8(b0, b1);
    }
    __syncthreads();
    short8 af[2], bfr[2];
#pragma unroll
    for (int ss = 0; ss < 2; ss++) {
      const int ra = wm*32 + ss*16 + lt;
      af[ss]  = *(const short8*)&As[ra][(g ^ ((ra & 3) ^ ((ra >> 2) & 3))) * 8];
      const int rb = wn*32 + ss*16 + lt;
      bfr[ss] = *(const short8*)&Bs[rb][(g ^ ((rb & 3) ^ ((rb >> 2) & 3))) * 8];
    }
#pragma unroll
    for (int i = 0; i < 2; i++)
#pragma unroll
      for (int j = 0; j < 2; j++)
        acc[i][j] = __builtin_amdgcn_mfma_f32_16x16x32_bf16(af[i], bfr[j], acc[i][j], 0, 0, 0);
    __syncthreads();
  }

#pragma unroll
  for (int i = 0; i < 2; i++)
#pragma unroll
    for (int j = 0; j < 2; j++) {
      const int n  = n0 + wn*32 + j*16 + lt;
      const float bv = bias[n];
      const int mb = m0 + wm*32 + i*16 + g*4;
#pragma unroll
      for (int r = 0; r < 4; r++) {
        const int mm = mb + r;
        if (EPI == 0) {
          const float val = (acc[i][j][r] + bv) * 0.17677669529663687f;
          const int bb = mm >> 9, s = mm & 511;
          const int d = n >> 8, ql = (n >> 3) & 31, hh = n & 7;
          const int tt = s*2 + d;
          ((ushort*)outp)[((size_t)(bb*8 + hh) * 1024 + tt) * 32 + ql] = f2bf(val);
        } else {
          ((float*)outp)[(size_t)mm * N + n] = acc[i][j][r] + bv;
        }
      }
    }
}

// ---------------------------------------------------------------------------
// Attention (split-n), t-PAIR per wave (R13 math/partials byte-identical).
// R14 scheduling: 4-buffer LDS ocs ring (32KB total -> 4 blocks/CU possible)
// with NS=8 (grid 1024 -> 4 blocks/CU offered). Per pair: issue [4 DMA for
// steps +2,+3] then [8 K/V for steps +2,+3] (pinned order); pair-end
// vmcnt(8) retires exactly those 4 DMAs (window = one t-pair body ~1400cyc
// > HBM latency), leaving all 8 K/V in flight until next-pair first use.
// Slot audit: pair reads slots s&3,(s+1)&3, DMAs write (s+2)&3,(s+3)&3 --
// disjoint; writes to slots last read in pair P-1 happen after its barrier.
// ---------------------------------------------------------------------------
__global__ __launch_bounds__(256) void attn_kernel(
    const ushort* __restrict__ qbf, const ushort* __restrict__ kbf,
    const ushort* __restrict__ vbf, const float* __restrict__ ocs,
    float* __restrict__ pacc, float* __restrict__ pl, int nsteps)
{
#if OCS_ASYNC
  __shared__ float obuf[4][2048];   // ring: 4 x [2 tiles][32 rows][8 slots][4 f32]
#endif
  const int tid  = threadIdx.x;
  const int lane = tid & 63;
  const int id = blockIdx.x;
  const int h   = id & 7;
  const int ttp = (id >> 3) & 15;
  const int c   = id >> 7;
  const int b  = tid >> 6;
  const int wid0 = ((h << 5) + 2*ttp) * 4 + b;   // tile0's wid; tile1 = wid0+4
  const int t0 = ttp * 64;
  const int lt = lane & 15, g = lane >> 4;
  const int n_start = c * nsteps * 32;

  const ushort* qp = qbf + (size_t)(b*8 + h) * (1024*32);
  const ushort* kp = kbf + (size_t)(b*8 + h) * (2048*32);
  const ushort* vp = vbf + (size_t)(b*8 + h) * (32*2048);
  const float*  op = ocs + (size_t)h * (1024*2048);

#define NSX(I) (((I) < nsteps) ? (n_start + (I)*32) : n_start)

  // ocs staging: thread -> row (tid>>3), slot (tid&7); source col is
  // inverse-swizzled so LDS slot s holds global cols 4*(s^(row&7))..+3.
  const int srow = tid >> 3;
  const int scol = 4 * ((tid & 7) ^ (srow & 7));
  const float* sb0 = op + (size_t)(t0 + srow) * 2048 + scol;
  const float* sb1 = op + (size_t)(t0 + 32 + srow) * 2048 + scol;
#if OCS_ASYNC
  const int ldsw = (tid & 192) * 16;   // per-wave LDS byte base (lane*16 added by HW)
#define SL_ISSUE(STEP) do {                                                   \
    gl_lds16(sb0 + NSX(STEP), (float*)((char*)obuf + (((STEP) & 3) << 13) + ldsw));        \
    gl_lds16(sb1 + NSX(STEP), (float*)((char*)obuf + (((STEP) & 3) << 13) + 4096 + ldsw)); \
  } while (0)
  // swizzled read offsets: sc0 cols 8g..8g+3 (slot 2g), sc1 cols 8g+4..8g+7
  // (slot 2g+1); row ts*16+lt.
  const int ro0 = lt * 128;            // ts=0 row byte offset
  const int ro1 = (16 + lt) * 128;     // ts=1
  const int c0x = ((2*g)     ^ (lt & 7)) * 16;   // sc0 slot bytes
  const int c1x = ((2*g + 1) ^ (lt & 7)) * 16;   // sc1 slot bytes
#define CO_READ(DST, TILE, STEP) do {                                         \
    const char* bb_ = (const char*)obuf + (((STEP) & 3) << 13) + ((TILE) << 12); \
    DST[0][0] = *(const f32x4*)(bb_ + ro0 + c0x);                             \
    DST[1][0] = *(const f32x4*)(bb_ + ro0 + c1x);                             \
    DST[0][1] = *(const f32x4*)(bb_ + ro1 + c0x);                             \
    DST[1][1] = *(const f32x4*)(bb_ + ro1 + c1x);                             \
  } while (0)
#define PAIR_SYNC() do {                                                      \
    __builtin_amdgcn_sched_barrier(0);                                        \
    asm volatile("s_waitcnt vmcnt(8)" ::: "memory");                          \
    __builtin_amdgcn_sched_barrier(0);                                        \
    __builtin_amdgcn_s_barrier();                                             \
  } while (0)
#else
#define SL_ISSUE(STEP)
#define CO_READ(DST, TILE, STEP) do {                                         \
    const int nn_ = NSX(STEP);                                                \
    const float* r0_ = op + (size_t)(t0 + (TILE)*32 + lt) * 2048 + nn_;       \
    const float* r1_ = op + (size_t)(t0 + (TILE)*32 + 16 + lt) * 2048 + nn_;  \
    DST[0][0] = *(const f32x4*)(r0_ + 8*g);                                   \
    DST[1][0] = *(const f32x4*)(r0_ + 8*g + 4);                               \
    DST[0][1] = *(const f32x4*)(r1_ + 8*g);                                   \
    DST[1][1] = *(const f32x4*)(r1_ + 8*g + 4);                               \
  } while (0)
#define PAIR_SYNC()
#endif

#define LD_KV(KD, VD, NN) do {                                                \
    KD[0] = *(const short8*)(kp + (size_t)((NN) + lt) * 32 + g*8);            \
    KD[1] = *(const short8*)(kp + (size_t)((NN) + 16 + lt) * 32 + g*8);       \
    VD[0] = *(const short8*)(vp + (size_t)lt * 2048 + (NN) + g*8);            \
    VD[1] = *(const short8*)(vp + (size_t)(16 + lt) * 2048 + (NN) + g*8);     \
  } while (0)

  short8 qf0[2], qf1[2];
#pragma unroll
  for (int ts = 0; ts < 2; ts++) {
    qf0[ts] = *(const short8*)(qp + (t0 + ts*16 + lt)*32 + g*8);
    qf1[ts] = *(const short8*)(qp + (t0 + 32 + ts*16 + lt)*32 + g*8);
  }

  f32x4 acc0[2][2] = {}, acc1[2][2] = {};
  float lsum0[2] = {0.f, 0.f}, lsum1[2] = {0.f, 0.f};
  const f32x4 fzero = {0.f, 0.f, 0.f, 0.f};

  // ts-block: exp + f2bf pack (P already in B-frag order via permuted K) + PV
#define TSB(SC0, SC1, CO0, CO1, VLO, VHI, LS, ACCA, ACCB) do {                \
    float p0 = __expf(SC0[0] - CO0[0]);                                       \
    float p1 = __expf(SC0[1] - CO0[1]);                                       \
    float p2 = __expf(SC0[2] - CO0[2]);                                       \
    float p3 = __expf(SC0[3] - CO0[3]);                                       \
    float p4 = __expf(SC1[0] - CO1[0]);                                       \
    float p5 = __expf(SC1[1] - CO1[1]);                                       \
    float p6 = __expf(SC1[2] - CO1[2]);                                       \
    float p7 = __expf(SC1[3] - CO1[3]);                                       \
    LS += ((p0+p1)+(p2+p3)) + ((p4+p5)+(p6+p7));                              \
    union { unsigned int u[4]; short8 s; } pf;                                \
    pf.u[0] = (unsigned int)f2bf(p0) | ((unsigned int)f2bf(p1) << 16);        \
    pf.u[1] = (unsigned int)f2bf(p2) | ((unsigned int)f2bf(p3) << 16);        \
    pf.u[2] = (unsigned int)f2bf(p4) | ((unsigned int)f2bf(p5) << 16);        \
    pf.u[3] = (unsigned int)f2bf(p6) | ((unsigned int)f2bf(p7) << 16);        \
    ACCA = __builtin_amdgcn_mfma_f32_16x16x32_bf16(VLO, pf.s, ACCA, 0, 0, 0); \
    ACCB = __builtin_amdgcn_mfma_f32_16x16x32_bf16(VHI, pf.s, ACCB, 0, 0, 0); \
  } while (0)

  // One step x one tile: 4 QK MFMAs, LDS co read, 2 TSBs (8 MFMA total).
#define STEPTILE(KC_, VC_, QFA, QFB, TILE, STEP, ACC, LS) do {                \
    f32x4 s0a = __builtin_amdgcn_mfma_f32_16x16x32_bf16(KC_[0], QFA, fzero, 0, 0, 0); \
    f32x4 s1a = __builtin_amdgcn_mfma_f32_16x16x32_bf16(KC_[1], QFA, fzero, 0, 0, 0); \
    f32x4 s0b = __builtin_amdgcn_mfma_f32_16x16x32_bf16(KC_[0], QFB, fzero, 0, 0, 0); \
    f32x4 s1b = __builtin_amdgcn_mfma_f32_16x16x32_bf16(KC_[1], QFB, fzero, 0, 0, 0); \
    f32x4 co[2][2];                                                           \
    CO_READ(co, TILE, STEP);                                                  \
    TSB(s0a, s1a, co[0][0], co[1][0], VC_[0], VC_[1], LS[0], ACC[0][0], ACC[0][1]); \
    TSB(s0b, s1b, co[0][1], co[1][1], VC_[0], VC_[1], LS[1], ACC[1][0], ACC[1][1]); \
  } while (0)

  // One pair = steps SA_, SA_+1 for BOTH tiles. Issues [4 DMA (steps +2,+3)]
  // then [8 K/V (+2,+3)]; pair-end vmcnt(8) retires exactly the 4 DMAs.
#define PAIR(SA_, KC, VC, KN, VN) do {                                        \
    const int sA_ = (SA_);                                                    \
    SL_ISSUE(sA_ + 2);                                                        \
    SL_ISSUE(sA_ + 3);                                                        \
    __builtin_amdgcn_sched_barrier(0);                                        \
    LD_KV(KN[0], VN[0], NSX(sA_ + 2));                                        \
    LD_KV(KN[1], VN[1], NSX(sA_ + 3));                                        \
    __builtin_amdgcn_sched_barrier(0);                                        \
    STEPTILE(KC[0], VC[0], qf0[0], qf0[1], 0, sA_,     acc0, lsum0);          \
    STEPTILE(KC[0], VC[0], qf1[0], qf1[1], 1, sA_,     acc1, lsum1);          \
    STEPTILE(KC[1], VC[1], qf0[0], qf0[1], 0, sA_ + 1, acc0, lsum0);          \
    STEPTILE(KC[1], VC[1], qf1[0], qf1[1], 1, sA_ + 1, acc1, lsum1);          \
    PAIR_SYNC();                                                              \
  } while (0)

  // named K/V register sets: K*[pair-step][half], V*[pair-step][half]
  short8 KA[2][2], VA[2][2], KB[2][2], VB[2][2];

  // prologue: DMA 0,1 first, then KV 0,1; vmcnt(8) retires the 4 DMAs.
#if OCS_ASYNC
  SL_ISSUE(0); SL_ISSUE(1);
  __builtin_amdgcn_sched_barrier(0);
#endif
  LD_KV(KA[0], VA[0], NSX(0));
  LD_KV(KA[1], VA[1], NSX(1));
#if OCS_ASYNC
  __builtin_amdgcn_sched_barrier(0);
  asm volatile("s_waitcnt vmcnt(8)" ::: "memory");
  __builtin_amdgcn_s_barrier();
#endif

  for (int s = 0; s < nsteps; s += 4) {
    PAIR(s,     KA, VA, KB, VB);   // steps s,s+1; stage s+2,s+3
    PAIR(s + 2, KB, VB, KA, VA);   // steps s+2,s+3; stage s+4,s+5
  }
#undef PAIR
#undef STEPTILE
#undef TSB
#undef LD_KV
#undef CO_READ
#undef SL_ISSUE
#undef PAIR_SYNC
#undef NSX

  // write partials for both tiles: rows [((c*1024+wid)*4 + q)*256 + lane*4]
  {
    float* pb0 = pacc + ((size_t)(c*1024 + wid0) * 4) * 256 + lane * 4;
    *(f32x4*)(pb0 + 0*256) = acc0[0][0];
    *(f32x4*)(pb0 + 1*256) = acc0[0][1];
    *(f32x4*)(pb0 + 2*256) = acc0[1][0];
    *(f32x4*)(pb0 + 3*256) = acc0[1][1];
    float* pb1 = pacc + ((size_t)(c*1024 + wid0 + 4) * 4) * 256 + lane * 4;
    *(f32x4*)(pb1 + 0*256) = acc1[0][0];
    *(f32x4*)(pb1 + 1*256) = acc1[0][1];
    *(f32x4*)(pb1 + 2*256) = acc1[1][0];
    *(f32x4*)(pb1 + 3*256) = acc1[1][1];
  }
  // reduce lsum over the 4 g-groups, store 32 per wid (both tiles)
#pragma unroll
  for (int ts = 0; ts < 2; ts++) {
    float L0 = lsum0[ts], L1 = lsum1[ts];
    L0 += __shfl_xor(L0, 16);  L0 += __shfl_xor(L0, 32);
    L1 += __shfl_xor(L1, 16);  L1 += __shfl_xor(L1, 32);
    if (g == 0) {
      pl[((size_t)(c*1024 + wid0)) * 32 + ts*16 + lt]     = L0;
      pl[((size_t)(c*1024 + wid0 + 4)) * 32 + ts*16 + lt] = L1;
    }
  }
}

// ---------------------------------------------------------------------------
// Combine partials across NS chunks, normalize, write vo[b*512+s][h*64+d*32+..]
// ---------------------------------------------------------------------------
__global__ __launch_bounds__(256) void combine_kernel(
    const float* __restrict__ pacc, const float* __restrict__ pl,
    float* __restrict__ vo, int NS)
{
  const int lane = threadIdx.x & 63;
  const int wid = blockIdx.x * 4 + (threadIdx.x >> 6);
  const int b  = wid & 3;
  const int tt = (wid >> 2) & 31;
  const int h  = wid >> 7;
  const int t0 = tt * 32;
  const int lt = lane & 15, g = lane >> 4;

  f32x4 acc[4] = {};
  float L[2] = {0.f, 0.f};
  for (int cc = 0; cc < NS; ++cc) {
    const float* pb = pacc + ((size_t)(cc*1024 + wid) * 4) * 256 + lane * 4;
#pragma unroll
    for (int q = 0; q < 4; q++) {
      f32x4 v = *(const f32x4*)(pb + q * 256);
#pragma unroll
      for (int r = 0; r < 4; r++) acc[q][r] += v[r];
    }
    L[0] += pl[((size_t)(cc*1024 + wid)) * 32 + lt];
    L[1] += pl[((size_t)(cc*1024 + wid)) * 32 + 16 + lt];
  }
#pragma unroll
  for (int ts = 0; ts < 2; ts++) {
    const float inv = 1.0f / L[ts];
    const int t = t0 + ts*16 + lt;
    const int s = t >> 1, d = t & 1;
    float* dst = vo + ((size_t)(b*512 + s) * 512) + h*64 + d*32;
#pragma unroll
    for (int vs = 0; vs < 2; vs++) {
      f32x4 o;
#pragma unroll
      for (int r = 0; r < 4; r++) o[r] = acc[ts*2 + vs][r] * inv;
      *(f32x4*)(dst + vs*16 + g*4) = o;
    }
  }
}

// ---------------------------------------------------------------------------
// LayerNorm over 512, one wave per row.
// ---------------------------------------------------------------------------
__global__ __launch_bounds__(256) void ln_kernel(
    const float* __restrict__ x_in, const float* __restrict__ gamma,
    const float* __restrict__ beta, float* __restrict__ x_out)
{
  const int row  = blockIdx.x * 4 + (threadIdx.x >> 6);
  const int lane = threadIdx.x & 63;
  const float* x = x_in + (size_t)row * 512 + lane * 8;
  f32x4 v0 = *(const f32x4*)x;
  f32x4 v1 = *(const f32x4*)(x + 4);
  float s = (v0[0]+v0[1]+v0[2]+v0[3]) + (v1[0]+v1[1]+v1[2]+v1[3]);
#pragma unroll
  for (int off = 1; off < 64; off <<= 1) s += __shfl_xor(s, off);
  const float mean = s * (1.0f/512.0f);
  float var = 0.f;
#pragma unroll
  for (int i = 0; i < 4; i++) {
    float d0 = v0[i]-mean, d1 = v1[i]-mean;
    var += d0*d0 + d1*d1;
  }
#pragma unroll
  for (int off = 1; off < 64; off <<= 1) var += __shfl_xor(var, off);
  const float rstd = rsqrtf(var * (1.0f/512.0f) + 1e-5f);
  const float* gp = gamma + lane*8;
  const float* bp = beta  + lane*8;
  f32x4 g0 = *(const f32x4*)gp, g1 = *(const f32x4*)(gp+4);
  f32x4 b0 = *(const f32x4*)bp, b1 = *(const f32x4*)(bp+4);
  f32x4 o0, o1;
#pragma unroll
  for (int i = 0; i < 4; i++) {
    o0[i] = (v0[i]-mean)*rstd*g0[i] + b0[i];
    o1[i] = (v1[i]-mean)*rstd*g1[i] + b1[i];
  }
  float* o = x_out + (size_t)row * 512 + lane * 8;
  *(f32x4*)o = o0;
  *(f32x4*)(o + 4) = o1;
}

// ---------------------------------------------------------------------------
extern "C" void kernel_launch(void* const* d_in, const int* in_sizes, int n_in,
                              void* d_out, int out_size, void* d_ws, size_t ws_size,
                              hipStream_t stream)
{
  const float* emb    = (const float*)d_in[0];
  const float* keys   = (const float*)d_in[1];
  const float* values = (const float*)d_in[2];
  const float* ocs    = (const float*)d_in[3];
  const float* Wq     = (const float*)d_in[4];
  const float* bq     = (const float*)d_in[5];
  const float* Wo     = (const float*)d_in[6];
  const float* bo     = (const float*)d_in[7];
  const float* gamma  = (const float*)d_in[8];
  const float* beta   = (const float*)d_in[9];

  char* ws = (char*)d_ws;
  ushort* qbf = (ushort*)(ws);                    // 2 MB  [b,h,t,ql] bf16
  ushort* kbf = (ushort*)(ws + (2u << 20));       // 4 MB  [b,h,n',ql] bf16 (permuted tiles)
  ushort* vbf = (ushort*)(ws + (6u << 20));       // 4 MB  [b,h,vl,n] bf16
  float*  vo  = (float*) (ws + (10u << 20));      // 4 MB  [m,512] f32
  const size_t pbase = (size_t)14u << 20;

  int NS;
  if      (ws_size >= ((size_t)48u << 20)) NS = 8;   // pacc 32MB + pl 1MB
  else if (ws_size >= ((size_t)31u << 20)) NS = 4;   // pacc 16MB + pl 0.5MB
  else if (ws_size >= ((size_t)23u << 20)) NS = 2;
  else                                     NS = 1;
  float* pacc = (float*)(ws + pbase);                            // NS*4MB
  float* pl   = (float*)(ws + pbase + (size_t)NS * (4u << 20));  // NS*128KB
  const int nsteps = 2048 / (NS * 32);

  prep_kv<<<dim3(256), dim3(256), 0, stream>>>(keys, values, kbf, vbf);
  gemm_nt<0><<<dim3(32, 8), dim3(256), 0, stream>>>(emb, Wq, bq, (void*)qbf, 2048, 512, 1024);
  attn_kernel<<<dim3(128 * NS), dim3(256), 0, stream>>>(qbf, kbf, vbf, ocs, pacc, pl, nsteps);
  combine_kernel<<<dim3(256), dim3(256), 0, stream>>>(pacc, pl, vo, NS);
  ln_kernel<<<dim3(512), dim3(256), 0, stream>>>(vo, gamma, beta, vo);
  gemm_nt<1><<<dim3(32, 16), dim3(256), 0, stream>>>(vo, Wo, bo, d_out, 2048, 1024, 512);
}

// Round 15
// 89.987 us; speedup vs baseline: 1.2227x; 1.0404x over previous
//
#include <hip/hip_runtime.h>
#include <hip/hip_bf16.h>

// Problem constants: B=4, S=512, N=2048, E=1024, QL=32, H=8, D=2, VL=32
// Inputs: 0 embeddings[4,512,1024] 1 keys[4,2048,256] 2 values[4,2048,256]
//         3 ocs[8,1024,2048] 4 Wq[512,1024] 5 bq[512] 6 Wo[1024,512] 7 bo[1024]
//         8 gamma[512] 9 beta[512]       all float32.  Output [4,512,1024] f32.

typedef short  short8 __attribute__((ext_vector_type(8)));
typedef float  f32x4  __attribute__((ext_vector_type(4)));

__device__ __forceinline__ ushort f2bf(float x) {
  union { float f; unsigned int u; } v; v.f = x;
  unsigned int r = v.u + 0x7fffu + ((v.u >> 16) & 1u);
  return (ushort)(r >> 16);
}

// hardware packed f32x2 -> bf16x2 (RNE), 1 instr. Used ONLY where the
// consumer is a DS/shuffle/store op (never directly feeding MFMA).
__device__ __forceinline__ unsigned int cvtpk(float a, float b) {
  unsigned int r;
  asm("v_cvt_pk_bf16_f32 %0, %1, %2" : "=v"(r) : "v"(a), "v"(b));
  return r;
}
__device__ __forceinline__ short8 cvt8(f32x4 a, f32x4 b) {
  union { unsigned int u[4]; short8 s; } r;
  r.u[0] = cvtpk(a[0], a[1]);
  r.u[1] = cvtpk(a[2], a[3]);
  r.u[2] = cvtpk(b[0], b[1]);
  r.u[3] = cvtpk(b[2], b[3]);
  return r.s;
}

#if __has_builtin(__builtin_amdgcn_global_load_lds)
#define OCS_ASYNC 1
__device__ __forceinline__ void gl_lds16(const float* g, float* l) {
  __builtin_amdgcn_global_load_lds(
      (const __attribute__((address_space(1))) unsigned int*)g,
      (__attribute__((address_space(3))) unsigned int*)l, 16, 0, 0);
}
#else
#define OCS_ASYNC 0
#endif

// ---------------------------------------------------------------------------
// prep: keys[b,n,ql*8+h] -> kbf[b,h,n',ql] (bf16) where within each 32-row
// tile, position p = 16s+4gg+r holds source row sigma(p) = 8gg+4s+r. This
// makes the QK^T MFMA output land directly in the K=32 PV B-fragment order
// (lane g holds n = 8g+0..3 from sc0 and 8g+4..7 from sc1) -- no shuffles.
// values[b,n,vl*8+h] -> vbf[b,h,vl,n] (unpermuted).
// ---------------------------------------------------------------------------
__global__ __launch_bounds__(256) void prep_kv(
    const float* __restrict__ keys, const float* __restrict__ values,
    ushort* __restrict__ kbf, ushort* __restrict__ vbf)
{
  __shared__ ushort T[32][264];
  const int bi = blockIdx.x;            // 0..255
  const int b  = bi >> 6;
  const int n0 = (bi & 63) * 32;
  const int t  = threadIdx.x;
  const int nr = t >> 3;                // 0..31
  const int c0 = (t & 7) * 32;          // 0..224

  {
    const float* src = keys + ((size_t)b*2048 + n0 + nr)*256 + c0;
#pragma unroll
    for (int j = 0; j < 32; j += 8) {
      f32x4 x0 = *(const f32x4*)(src + j);
      f32x4 x1 = *(const f32x4*)(src + j + 4);
      *(short8*)&T[nr][c0 + j] = cvt8(x0, x1);
    }
  }
  __syncthreads();
  {
    const int h = t >> 5, nn = t & 31;
    // inverse permutation: source row nn -> tile position pp
    const int pp = 16*((nn >> 2) & 1) + 4*(nn >> 3) + (nn & 3);
    ushort* dst = kbf + (((size_t)(b*8 + h) * 2048) + n0 + pp) * 32;
#pragma unroll
    for (int j = 0; j < 4; j++) {
      short8 w;
#pragma unroll
      for (int i = 0; i < 8; i++) w[i] = (short)T[nn][(j*8 + i)*8 + h];
      *(short8*)(dst + j*8) = w;
    }
  }
  __syncthreads();
  {
    const float* src = values + ((size_t)b*2048 + n0 + nr)*256 + c0;
#pragma unroll
    for (int j = 0; j < 32; j += 8) {
      f32x4 x0 = *(const f32x4*)(src + j);
      f32x4 x1 = *(const f32x4*)(src + j + 4);
      *(short8*)&T[nr][c0 + j] = cvt8(x0, x1);
    }
  }
  __syncthreads();
  {
    const int c = t, h = c & 7, vl = c >> 3;
    ushort* dst = vbf + (((size_t)(b*8 + h) * 32) + vl) * 2048 + n0;
#pragma unroll
    for (int j = 0; j < 4; j++) {
      short8 w;
#pragma unroll
      for (int i = 0; i < 8; i++) w[i] = (short)T[j*8 + i][c];
      *(short8*)(dst + j*8) = w;
    }
  }
}

// ---------------------------------------------------------------------------
// GEMM (NT): out[m,n] = sum_k A[m,k]*B[n,k] + bias[n]. 64x64 tile, 4 waves.
// R15: software-pipelined staging -- double-buffered LDS (2x), prefetch
// distance 1 K-step into named regs, RAW s_barrier (no vmcnt(0) drain, so
// the k+1 global loads stay in flight under step k's ds_read+MFMA); explicit
// lgkmcnt(0) before the write-side barrier only.
// EPI=0: scatter-store bf16*(1/sqrt(32)) into qbf[b,h,t,ql]; EPI=1: f32 out.
// ---------------------------------------------------------------------------
template<int EPI>
__global__ __launch_bounds__(256) void gemm_nt(
    const float* __restrict__ A, const float* __restrict__ Bm,
    const float* __restrict__ bias, void* __restrict__ outp,
    int M, int N, int K)
{
  __shared__ ushort As[2][64][32];
  __shared__ ushort Bs[2][64][32];
  const int tid = threadIdx.x;
  const int m0 = blockIdx.x * 64;
  const int n0 = blockIdx.y * 64;
  const int lane = tid & 63;
  const int wid  = tid >> 6;
  const int wm = wid >> 1, wn = wid & 1;
  const int lt = lane & 15, g = lane >> 4;
  const int lrow = tid >> 2;      // 0..63
  const int lseg = tid & 3;       // 0..3 (8 floats each)
  const int slot_w = lseg ^ ((lrow & 3) ^ ((lrow >> 2) & 3));
  const int sa_r = (g ^ ((( wm*32 + lt) & 3) ^ (((wm*32 + lt) >> 2) & 3)));   // unused helper; kept simple below

  f32x4 acc[2][2] = {};
  f32x4 pa0, pa1, pb0, pb1;     // named prefetch registers

#define GLOAD(K0) do {                                                        \
    const float* sa_ = A  + (size_t)(m0 + lrow) * K + (K0) + lseg * 8;        \
    pa0 = *(const f32x4*)sa_;  pa1 = *(const f32x4*)(sa_ + 4);                \
    const float* sb_ = Bm + (size_t)(n0 + lrow) * K + (K0) + lseg * 8;        \
    pb0 = *(const f32x4*)sb_;  pb1 = *(const f32x4*)(sb_ + 4);                \
  } while (0)
#define SWRITE(BUF) do {                                                      \
    *(short8*)&As[BUF][lrow][slot_w * 8] = cvt8(pa0, pa1);                    \
    *(short8*)&Bs[BUF][lrow][slot_w * 8] = cvt8(pb0, pb1);                    \
  } while (0)

  // prologue: stage k=0 into buf 0 (full drain once is fine)
  GLOAD(0);
  SWRITE(0);
  __syncthreads();

  int cur = 0;
  for (int k0 = 0; k0 < K; k0 += 32) {
    const bool more = (k0 + 32 < K);
    if (more) GLOAD(k0 + 32);          // in flight across barrier1
    short8 af[2], bfr[2];
#pragma unroll
    for (int ss = 0; ss < 2; ss++) {
      const int ra = wm*32 + ss*16 + lt;
      af[ss]  = *(const short8*)&As[cur][ra][(g ^ ((ra & 3) ^ ((ra >> 2) & 3))) * 8];
      const int rb = wn*32 + ss*16 + lt;
      bfr[ss] = *(const short8*)&Bs[cur][rb][(g ^ ((rb & 3) ^ ((rb >> 2) & 3))) * 8];
    }
#pragma unroll
    for (int i = 0; i < 2; i++)
#pragma unroll
      for (int j = 0; j < 2; j++)
        acc[i][j] = __builtin_amdgcn_mfma_f32_16x16x32_bf16(af[i], bfr[j], acc[i][j], 0, 0, 0);
    // barrier1: every wave's ds_reads of buf[cur] completed (MFMA waited on
    // them); raw barrier leaves the k+1 global loads in flight.
    asm volatile("s_barrier" ::: "memory");
    if (more) {
      SWRITE(cur ^ 1);                 // vmcnt wait lands here, mostly hidden
      asm volatile("s_waitcnt lgkmcnt(0)" ::: "memory");
    }
    asm volatile("s_barrier" ::: "memory");   // barrier2: buf[cur^1] ready
    cur ^= 1;
  }

#pragma unroll
  for (int i = 0; i < 2; i++)
#pragma unroll
    for (int j = 0; j < 2; j++) {
      const int n  = n0 + wn*32 + j*16 + lt;
      const float bv = bias[n];
      const int mb = m0 + wm*32 + i*16 + g*4;
#pragma unroll
      for (int r = 0; r < 4; r++) {
        const int mm = mb + r;
        if (EPI == 0) {
          const float val = (acc[i][j][r] + bv) * 0.17677669529663687f;
          const int bb = mm >> 9, s = mm & 511;
          const int d = n >> 8, ql = (n >> 3) & 31, hh = n & 7;
          const int tt = s*2 + d;
          ((ushort*)outp)[((size_t)(bb*8 + hh) * 1024 + tt) * 32 + ql] = f2bf(val);
        } else {
          ((float*)outp)[(size_t)mm * N + n] = acc[i][j][r] + bv;
        }
      }
    }
#undef GLOAD
#undef SWRITE
}

// ---------------------------------------------------------------------------
// Attention (split-n), t-PAIR per wave (R13 math/partials byte-identical).
// R14 scheduling: 4-buffer LDS ocs ring (32KB total -> 4 blocks/CU possible)
// with NS=8 (grid 1024 -> 4 blocks/CU offered). Per pair: issue [4 DMA for
// steps +2,+3] then [8 K/V for steps +2,+3] (pinned order); pair-end
// vmcnt(8) retires exactly those 4 DMAs (window = one t-pair body ~1400cyc
// > HBM latency), leaving all 8 K/V in flight until next-pair first use.
// Slot audit: pair reads slots s&3,(s+1)&3, DMAs write (s+2)&3,(s+3)&3 --
// disjoint; writes to slots last read in pair P-1 happen after its barrier.
// ---------------------------------------------------------------------------
__global__ __launch_bounds__(256) void attn_kernel(
    const ushort* __restrict__ qbf, const ushort* __restrict__ kbf,
    const ushort* __restrict__ vbf, const float* __restrict__ ocs,
    float* __restrict__ pacc, float* __restrict__ pl, int nsteps)
{
#if OCS_ASYNC
  __shared__ float obuf[4][2048];   // ring: 4 x [2 tiles][32 rows][8 slots][4 f32]
#endif
  const int tid  = threadIdx.x;
  const int lane = tid & 63;
  const int id = blockIdx.x;
  const int h   = id & 7;
  const int ttp = (id >> 3) & 15;
  const int c   = id >> 7;
  const int b  = tid >> 6;
  const int wid0 = ((h << 5) + 2*ttp) * 4 + b;   // tile0's wid; tile1 = wid0+4
  const int t0 = ttp * 64;
  const int lt = lane & 15, g = lane >> 4;
  const int n_start = c * nsteps * 32;

  const ushort* qp = qbf + (size_t)(b*8 + h) * (1024*32);
  const ushort* kp = kbf + (size_t)(b*8 + h) * (2048*32);
  const ushort* vp = vbf + (size_t)(b*8 + h) * (32*2048);
  const float*  op = ocs + (size_t)h * (1024*2048);

#define NSX(I) (((I) < nsteps) ? (n_start + (I)*32) : n_start)

  // ocs staging: thread -> row (tid>>3), slot (tid&7); source col is
  // inverse-swizzled so LDS slot s holds global cols 4*(s^(row&7))..+3.
  const int srow = tid >> 3;
  const int scol = 4 * ((tid & 7) ^ (srow & 7));
  const float* sb0 = op + (size_t)(t0 + srow) * 2048 + scol;
  const float* sb1 = op + (size_t)(t0 + 32 + srow) * 2048 + scol;
#if OCS_ASYNC
  const int ldsw = (tid & 192) * 16;   // per-wave LDS byte base (lane*16 added by HW)
#define SL_ISSUE(STEP) do {                                                   \
    gl_lds16(sb0 + NSX(STEP), (float*)((char*)obuf + (((STEP) & 3) << 13) + ldsw));        \
    gl_lds16(sb1 + NSX(STEP), (float*)((char*)obuf + (((STEP) & 3) << 13) + 4096 + ldsw)); \
  } while (0)
  // swizzled read offsets: sc0 cols 8g..8g+3 (slot 2g), sc1 cols 8g+4..8g+7
  // (slot 2g+1); row ts*16+lt.
  const int ro0 = lt * 128;            // ts=0 row byte offset
  const int ro1 = (16 + lt) * 128;     // ts=1
  const int c0x = ((2*g)     ^ (lt & 7)) * 16;   // sc0 slot bytes
  const int c1x = ((2*g + 1) ^ (lt & 7)) * 16;   // sc1 slot bytes
#define CO_READ(DST, TILE, STEP) do {                                         \
    const char* bb_ = (const char*)obuf + (((STEP) & 3) << 13) + ((TILE) << 12); \
    DST[0][0] = *(const f32x4*)(bb_ + ro0 + c0x);                             \
    DST[1][0] = *(const f32x4*)(bb_ + ro0 + c1x);                             \
    DST[0][1] = *(const f32x4*)(bb_ + ro1 + c0x);                             \
    DST[1][1] = *(const f32x4*)(bb_ + ro1 + c1x);                             \
  } while (0)
#define PAIR_SYNC() do {                                                      \
    __builtin_amdgcn_sched_barrier(0);                                        \
    asm volatile("s_waitcnt vmcnt(8)" ::: "memory");                          \
    __builtin_amdgcn_sched_barrier(0);                                        \
    __builtin_amdgcn_s_barrier();                                             \
  } while (0)
#else
#define SL_ISSUE(STEP)
#define CO_READ(DST, TILE, STEP) do {                                         \
    const int nn_ = NSX(STEP);                                                \
    const float* r0_ = op + (size_t)(t0 + (TILE)*32 + lt) * 2048 + nn_;       \
    const float* r1_ = op + (size_t)(t0 + (TILE)*32 + 16 + lt) * 2048 + nn_;  \
    DST[0][0] = *(const f32x4*)(r0_ + 8*g);                                   \
    DST[1][0] = *(const f32x4*)(r0_ + 8*g + 4);                               \
    DST[0][1] = *(const f32x4*)(r1_ + 8*g);                                   \
    DST[1][1] = *(const f32x4*)(r1_ + 8*g + 4);                               \
  } while (0)
#define PAIR_SYNC()
#endif

#define LD_KV(KD, VD, NN) do {                                                \
    KD[0] = *(const short8*)(kp + (size_t)((NN) + lt) * 32 + g*8);            \
    KD[1] = *(const short8*)(kp + (size_t)((NN) + 16 + lt) * 32 + g*8);       \
    VD[0] = *(const short8*)(vp + (size_t)lt * 2048 + (NN) + g*8);            \
    VD[1] = *(const short8*)(vp + (size_t)(16 + lt) * 2048 + (NN) + g*8);     \
  } while (0)

  short8 qf0[2], qf1[2];
#pragma unroll
  for (int ts = 0; ts < 2; ts++) {
    qf0[ts] = *(const short8*)(qp + (t0 + ts*16 + lt)*32 + g*8);
    qf1[ts] = *(const short8*)(qp + (t0 + 32 + ts*16 + lt)*32 + g*8);
  }

  f32x4 acc0[2][2] = {}, acc1[2][2] = {};
  float lsum0[2] = {0.f, 0.f}, lsum1[2] = {0.f, 0.f};
  const f32x4 fzero = {0.f, 0.f, 0.f, 0.f};

  // ts-block: exp + f2bf pack (P already in B-frag order via permuted K) + PV
#define TSB(SC0, SC1, CO0, CO1, VLO, VHI, LS, ACCA, ACCB) do {                \
    float p0 = __expf(SC0[0] - CO0[0]);                                       \
    float p1 = __expf(SC0[1] - CO0[1]);                                       \
    float p2 = __expf(SC0[2] - CO0[2]);                                       \
    float p3 = __expf(SC0[3] - CO0[3]);                                       \
    float p4 = __expf(SC1[0] - CO1[0]);                                       \
    float p5 = __expf(SC1[1] - CO1[1]);                                       \
    float p6 = __expf(SC1[2] - CO1[2]);                                       \
    float p7 = __expf(SC1[3] - CO1[3]);                                       \
    LS += ((p0+p1)+(p2+p3)) + ((p4+p5)+(p6+p7));                              \
    union { unsigned int u[4]; short8 s; } pf;                                \
    pf.u[0] = (unsigned int)f2bf(p0) | ((unsigned int)f2bf(p1) << 16);        \
    pf.u[1] = (unsigned int)f2bf(p2) | ((unsigned int)f2bf(p3) << 16);        \
    pf.u[2] = (unsigned int)f2bf(p4) | ((unsigned int)f2bf(p5) << 16);        \
    pf.u[3] = (unsigned int)f2bf(p6) | ((unsigned int)f2bf(p7) << 16);        \
    ACCA = __builtin_amdgcn_mfma_f32_16x16x32_bf16(VLO, pf.s, ACCA, 0, 0, 0); \
    ACCB = __builtin_amdgcn_mfma_f32_16x16x32_bf16(VHI, pf.s, ACCB, 0, 0, 0); \
  } while (0)

  // One step x one tile: 4 QK MFMAs, LDS co read, 2 TSBs (8 MFMA total).
#define STEPTILE(KC_, VC_, QFA, QFB, TILE, STEP, ACC, LS) do {                \
    f32x4 s0a = __builtin_amdgcn_mfma_f32_16x16x32_bf16(KC_[0], QFA, fzero, 0, 0, 0); \
    f32x4 s1a = __builtin_amdgcn_mfma_f32_16x16x32_bf16(KC_[1], QFA, fzero, 0, 0, 0); \
    f32x4 s0b = __builtin_amdgcn_mfma_f32_16x16x32_bf16(KC_[0], QFB, fzero, 0, 0, 0); \
    f32x4 s1b = __builtin_amdgcn_mfma_f32_16x16x32_bf16(KC_[1], QFB, fzero, 0, 0, 0); \
    f32x4 co[2][2];                                                           \
    CO_READ(co, TILE, STEP);                                                  \
    TSB(s0a, s1a, co[0][0], co[1][0], VC_[0], VC_[1], LS[0], ACC[0][0], ACC[0][1]); \
    TSB(s0b, s1b, co[0][1], co[1][1], VC_[0], VC_[1], LS[1], ACC[1][0], ACC[1][1]); \
  } while (0)

  // One pair = steps SA_, SA_+1 for BOTH tiles. Issues [4 DMA (steps +2,+3)]
  // then [8 K/V (+2,+3)]; pair-end vmcnt(8) retires exactly the 4 DMAs.
#define PAIR(SA_, KC, VC, KN, VN) do {                                        \
    const int sA_ = (SA_);                                                    \
    SL_ISSUE(sA_ + 2);                                                        \
    SL_ISSUE(sA_ + 3);                                                        \
    __builtin_amdgcn_sched_barrier(0);                                        \
    LD_KV(KN[0], VN[0], NSX(sA_ + 2));                                        \
    LD_KV(KN[1], VN[1], NSX(sA_ + 3));                                        \
    __builtin_amdgcn_sched_barrier(0);                                        \
    STEPTILE(KC[0], VC[0], qf0[0], qf0[1], 0, sA_,     acc0, lsum0);          \
    STEPTILE(KC[0], VC[0], qf1[0], qf1[1], 1, sA_,     acc1, lsum1);          \
    STEPTILE(KC[1], VC[1], qf0[0], qf0[1], 0, sA_ + 1, acc0, lsum0);          \
    STEPTILE(KC[1], VC[1], qf1[0], qf1[1], 1, sA_ + 1, acc1, lsum1);          \
    PAIR_SYNC();                                                              \
  } while (0)

  // named K/V register sets: K*[pair-step][half], V*[pair-step][half]
  short8 KA[2][2], VA[2][2], KB[2][2], VB[2][2];

  // prologue: DMA 0,1 first, then KV 0,1; vmcnt(8) retires the 4 DMAs.
#if OCS_ASYNC
  SL_ISSUE(0); SL_ISSUE(1);
  __builtin_amdgcn_sched_barrier(0);
#endif
  LD_KV(KA[0], VA[0], NSX(0));
  LD_KV(KA[1], VA[1], NSX(1));
#if OCS_ASYNC
  __builtin_amdgcn_sched_barrier(0);
  asm volatile("s_waitcnt vmcnt(8)" ::: "memory");
  __builtin_amdgcn_s_barrier();
#endif

  for (int s = 0; s < nsteps; s += 4) {
    PAIR(s,     KA, VA, KB, VB);   // steps s,s+1; stage s+2,s+3
    PAIR(s + 2, KB, VB, KA, VA);   // steps s+2,s+3; stage s+4,s+5
  }
#undef PAIR
#undef STEPTILE
#undef TSB
#undef LD_KV
#undef CO_READ
#undef SL_ISSUE
#undef PAIR_SYNC
#undef NSX

  // write partials for both tiles: rows [((c*1024+wid)*4 + q)*256 + lane*4]
  {
    float* pb0 = pacc + ((size_t)(c*1024 + wid0) * 4) * 256 + lane * 4;
    *(f32x4*)(pb0 + 0*256) = acc0[0][0];
    *(f32x4*)(pb0 + 1*256) = acc0[0][1];
    *(f32x4*)(pb0 + 2*256) = acc0[1][0];
    *(f32x4*)(pb0 + 3*256) = acc0[1][1];
    float* pb1 = pacc + ((size_t)(c*1024 + wid0 + 4) * 4) * 256 + lane * 4;
    *(f32x4*)(pb1 + 0*256) = acc1[0][0];
    *(f32x4*)(pb1 + 1*256) = acc1[0][1];
    *(f32x4*)(pb1 + 2*256) = acc1[1][0];
    *(f32x4*)(pb1 + 3*256) = acc1[1][1];
  }
  // reduce lsum over the 4 g-groups, store 32 per wid (both tiles)
#pragma unroll
  for (int ts = 0; ts < 2; ts++) {
    float L0 = lsum0[ts], L1 = lsum1[ts];
    L0 += __shfl_xor(L0, 16);  L0 += __shfl_xor(L0, 32);
    L1 += __shfl_xor(L1, 16);  L1 += __shfl_xor(L1, 32);
    if (g == 0) {
      pl[((size_t)(c*1024 + wid0)) * 32 + ts*16 + lt]     = L0;
      pl[((size_t)(c*1024 + wid0 + 4)) * 32 + ts*16 + lt] = L1;
    }
  }
}

// ---------------------------------------------------------------------------
// Combine partials across NS chunks, normalize, write vo[b*512+s][h*64+d*32+..]
// ---------------------------------------------------------------------------
__global__ __launch_bounds__(256) void combine_kernel(
    const float* __restrict__ pacc, const float* __restrict__ pl,
    float* __restrict__ vo, int NS)
{
  const int lane = threadIdx.x & 63;
  const int wid = blockIdx.x * 4 + (threadIdx.x >> 6);
  const int b  = wid & 3;
  const int tt = (wid >> 2) & 31;
  const int h  = wid >> 7;
  const int t0 = tt * 32;
  const int lt = lane & 15, g = lane >> 4;

  f32x4 acc[4] = {};
  float L[2] = {0.f, 0.f};
  for (int cc = 0; cc < NS; ++cc) {
    const float* pb = pacc + ((size_t)(cc*1024 + wid) * 4) * 256 + lane * 4;
#pragma unroll
    for (int q = 0; q < 4; q++) {
      f32x4 v = *(const f32x4*)(pb + q * 256);
#pragma unroll
      for (int r = 0; r < 4; r++) acc[q][r] += v[r];
    }
    L[0] += pl[((size_t)(cc*1024 + wid)) * 32 + lt];
    L[1] += pl[((size_t)(cc*1024 + wid)) * 32 + 16 + lt];
  }
#pragma unroll
  for (int ts = 0; ts < 2; ts++) {
    const float inv = 1.0f / L[ts];
    const int t = t0 + ts*16 + lt;
    const int s = t >> 1, d = t & 1;
    float* dst = vo + ((size_t)(b*512 + s) * 512) + h*64 + d*32;
#pragma unroll
    for (int vs = 0; vs < 2; vs++) {
      f32x4 o;
#pragma unroll
      for (int r = 0; r < 4; r++) o[r] = acc[ts*2 + vs][r] * inv;
      *(f32x4*)(dst + vs*16 + g*4) = o;
    }
  }
}

// ---------------------------------------------------------------------------
// LayerNorm over 512, one wave per row.
// ---------------------------------------------------------------------------
__global__ __launch_bounds__(256) void ln_kernel(
    const float* __restrict__ x_in, const float* __restrict__ gamma,
    const float* __restrict__ beta, float* __restrict__ x_out)
{
  const int row  = blockIdx.x * 4 + (threadIdx.x >> 6);
  const int lane = threadIdx.x & 63;
  const float* x = x_in + (size_t)row * 512 + lane * 8;
  f32x4 v0 = *(const f32x4*)x;
  f32x4 v1 = *(const f32x4*)(x + 4);
  float s = (v0[0]+v0[1]+v0[2]+v0[3]) + (v1[0]+v1[1]+v1[2]+v1[3]);
#pragma unroll
  for (int off = 1; off < 64; off <<= 1) s += __shfl_xor(s, off);
  const float mean = s * (1.0f/512.0f);
  float var = 0.f;
#pragma unroll
  for (int i = 0; i < 4; i++) {
    float d0 = v0[i]-mean, d1 = v1[i]-mean;
    var += d0*d0 + d1*d1;
  }
#pragma unroll
  for (int off = 1; off < 64; off <<= 1) var += __shfl_xor(var, off);
  const float rstd = rsqrtf(var * (1.0f/512.0f) + 1e-5f);
  const float* gp = gamma + lane*8;
  const float* bp = beta  + lane*8;
  f32x4 g0 = *(const f32x4*)gp, g1 = *(const f32x4*)(gp+4);
  f32x4 b0 = *(const f32x4*)bp, b1 = *(const f32x4*)(bp+4);
  f32x4 o0, o1;
#pragma unroll
  for (int i = 0; i < 4; i++) {
    o0[i] = (v0[i]-mean)*rstd*g0[i] + b0[i];
    o1[i] = (v1[i]-mean)*rstd*g1[i] + b1[i];
  }
  float* o = x_out + (size_t)row * 512 + lane * 8;
  *(f32x4*)o = o0;
  *(f32x4*)(o + 4) = o1;
}

// ---------------------------------------------------------------------------
extern "C" void kernel_launch(void* const* d_in, const int* in_sizes, int n_in,
                              void* d_out, int out_size, void* d_ws, size_t ws_size,
                              hipStream_t stream)
{
  const float* emb    = (const float*)d_in[0];
  const float* keys   = (const float*)d_in[1];
  const float* values = (const float*)d_in[2];
  const float* ocs    = (const float*)d_in[3];
  const float* Wq     = (const float*)d_in[4];
  const float* bq     = (const float*)d_in[5];
  const float* Wo     = (const float*)d_in[6];
  const float* bo     = (const float*)d_in[7];
  const float* gamma  = (const float*)d_in[8];
  const float* beta   = (const float*)d_in[9];

  char* ws = (char*)d_ws;
  ushort* qbf = (ushort*)(ws);                    // 2 MB  [b,h,t,ql] bf16
  ushort* kbf = (ushort*)(ws + (2u << 20));       // 4 MB  [b,h,n',ql] bf16 (permuted tiles)
  ushort* vbf = (ushort*)(ws + (6u << 20));       // 4 MB  [b,h,vl,n] bf16
  float*  vo  = (float*) (ws + (10u << 20));      // 4 MB  [m,512] f32
  const size_t pbase = (size_t)14u << 20;

  int NS;
  if      (ws_size >= ((size_t)48u << 20)) NS = 8;   // pacc 32MB + pl 1MB
  else if (ws_size >= ((size_t)31u << 20)) NS = 4;   // pacc 16MB + pl 0.5MB
  else if (ws_size >= ((size_t)23u << 20)) NS = 2;
  else                                     NS = 1;
  float* pacc = (float*)(ws + pbase);                            // NS*4MB
  float* pl   = (float*)(ws + pbase + (size_t)NS * (4u << 20));  // NS*128KB
  const int nsteps = 2048 / (NS * 32);

  prep_kv<<<dim3(256), dim3(256), 0, stream>>>(keys, values, kbf, vbf);
  gemm_nt<0><<<dim3(32, 8), dim3(256), 0, stream>>>(emb, Wq, bq, (void*)qbf, 2048, 512, 1024);
  attn_kernel<<<dim3(128 * NS), dim3(256), 0, stream>>>(qbf, kbf, vbf, ocs, pacc, pl, nsteps);
  combine_kernel<<<dim3(256), dim3(256), 0, stream>>>(pacc, pl, vo, NS);
  ln_kernel<<<dim3(512), dim3(256), 0, stream>>>(vo, gamma, beta, vo);
  gemm_nt<1><<<dim3(32, 16), dim3(256), 0, stream>>>(vo, Wo, bo, d_out, 2048, 1024, 512);
}

// Round 16
// 86.495 us; speedup vs baseline: 1.2720x; 1.0404x over previous
//
#include <hip/hip_runtime.h>
#include <hip/hip_bf16.h>

// Problem constants: B=4, S=512, N=2048, E=1024, QL=32, H=8, D=2, VL=32
// Inputs: 0 embeddings[4,512,1024] 1 keys[4,2048,256] 2 values[4,2048,256]
//         3 ocs[8,1024,2048] 4 Wq[512,1024] 5 bq[512] 6 Wo[1024,512] 7 bo[1024]
//         8 gamma[512] 9 beta[512]       all float32.  Output [4,512,1024] f32.

typedef short  short8 __attribute__((ext_vector_type(8)));
typedef float  f32x4  __attribute__((ext_vector_type(4)));

__device__ __forceinline__ ushort f2bf(float x) {
  union { float f; unsigned int u; } v; v.f = x;
  unsigned int r = v.u + 0x7fffu + ((v.u >> 16) & 1u);
  return (ushort)(r >> 16);
}

// hardware packed f32x2 -> bf16x2 (RNE), 1 instr. Used ONLY where the
// consumer is a DS/shuffle/store op (never directly feeding MFMA).
__device__ __forceinline__ unsigned int cvtpk(float a, float b) {
  unsigned int r;
  asm("v_cvt_pk_bf16_f32 %0, %1, %2" : "=v"(r) : "v"(a), "v"(b));
  return r;
}
__device__ __forceinline__ short8 cvt8(f32x4 a, f32x4 b) {
  union { unsigned int u[4]; short8 s; } r;
  r.u[0] = cvtpk(a[0], a[1]);
  r.u[1] = cvtpk(a[2], a[3]);
  r.u[2] = cvtpk(b[0], b[1]);
  r.u[3] = cvtpk(b[2], b[3]);
  return r.s;
}

#if __has_builtin(__builtin_amdgcn_global_load_lds)
#define OCS_ASYNC 1
__device__ __forceinline__ void gl_lds16(const float* g, float* l) {
  __builtin_amdgcn_global_load_lds(
      (const __attribute__((address_space(1))) unsigned int*)g,
      (__attribute__((address_space(3))) unsigned int*)l, 16, 0, 0);
}
#else
#define OCS_ASYNC 0
#endif

// ---------------------------------------------------------------------------
// prep body: keys[b,n,ql*8+h] -> kbf[b,h,n',ql] (permuted tiles: position
// p = 16s+4gg+r holds source row 8gg+4s+r, so QK^T output lands directly in
// the K=32 PV B-fragment order); values -> vbf[b,h,vl,n].
// ---------------------------------------------------------------------------
__device__ __forceinline__ void prep_body(
    char* smem, int bi,
    const float* __restrict__ keys, const float* __restrict__ values,
    ushort* __restrict__ kbf, ushort* __restrict__ vbf)
{
  ushort (*T)[264] = (ushort (*)[264])smem;    // [32][264]
  const int b  = bi >> 6;
  const int n0 = (bi & 63) * 32;
  const int t  = threadIdx.x;
  const int nr = t >> 3;                // 0..31
  const int c0 = (t & 7) * 32;          // 0..224

  {
    const float* src = keys + ((size_t)b*2048 + n0 + nr)*256 + c0;
#pragma unroll
    for (int j = 0; j < 32; j += 8) {
      f32x4 x0 = *(const f32x4*)(src + j);
      f32x4 x1 = *(const f32x4*)(src + j + 4);
      *(short8*)&T[nr][c0 + j] = cvt8(x0, x1);
    }
  }
  __syncthreads();
  {
    const int h = t >> 5, nn = t & 31;
    const int pp = 16*((nn >> 2) & 1) + 4*(nn >> 3) + (nn & 3);
    ushort* dst = kbf + (((size_t)(b*8 + h) * 2048) + n0 + pp) * 32;
#pragma unroll
    for (int j = 0; j < 4; j++) {
      short8 w;
#pragma unroll
      for (int i = 0; i < 8; i++) w[i] = (short)T[nn][(j*8 + i)*8 + h];
      *(short8*)(dst + j*8) = w;
    }
  }
  __syncthreads();
  {
    const float* src = values + ((size_t)b*2048 + n0 + nr)*256 + c0;
#pragma unroll
    for (int j = 0; j < 32; j += 8) {
      f32x4 x0 = *(const f32x4*)(src + j);
      f32x4 x1 = *(const f32x4*)(src + j + 4);
      *(short8*)&T[nr][c0 + j] = cvt8(x0, x1);
    }
  }
  __syncthreads();
  {
    const int c = t, h = c & 7, vl = c >> 3;
    ushort* dst = vbf + (((size_t)(b*8 + h) * 32) + vl) * 2048 + n0;
#pragma unroll
    for (int j = 0; j < 4; j++) {
      short8 w;
#pragma unroll
      for (int i = 0; i < 8; i++) w[i] = (short)T[j*8 + i][c];
      *(short8*)(dst + j*8) = w;
    }
  }
}

// ---------------------------------------------------------------------------
// GEMM body (NT): out[m,n] = sum_k A'[m,k]*B[n,k] + bias[n]. 64x64 tile,
// 4 waves, R15-proven pipeline: double-buffered LDS, prefetch distance 1,
// raw s_barrier (no vmcnt drain), lgkmcnt(0) before write-side barrier.
// EPI=0: A'=A; scatter-store bf16*(1/sqrt32) into qbf.
// EPI=1: A'[m,k] = (A[m,k]-mean[m])*rstd[m]*gamma[k]+beta[k] (fused LN);
//        f32 row-major out.
// ---------------------------------------------------------------------------
template<int EPI>
__device__ __forceinline__ void gemm_body(
    char* smem,
    const float* __restrict__ A, const float* __restrict__ Bm,
    const float* __restrict__ bias, void* __restrict__ outp,
    int M, int N, int K, int m0, int n0,
    const float* __restrict__ lnmean, const float* __restrict__ lnrstd,
    const float* __restrict__ gamma,  const float* __restrict__ beta)
{
  ushort* As = (ushort*)smem;            // [2][64][32]
  ushort* Bs = (ushort*)(smem + 8192);   // [2][64][32]
  const int tid = threadIdx.x;
  const int lane = tid & 63;
  const int wid  = tid >> 6;
  const int wm = wid >> 1, wn = wid & 1;
  const int lt = lane & 15, g = lane >> 4;
  const int lrow = tid >> 2;      // 0..63
  const int lseg = tid & 3;       // 0..3 (8 floats each)
  const int slot_w = lseg ^ ((lrow & 3) ^ ((lrow >> 2) & 3));

  f32x4 acc[2][2] = {};
  f32x4 pa0, pa1, pb0, pb1;     // named prefetch registers

  float mean_r = 0.f, rstd_r = 1.f;
  if (EPI == 1) { mean_r = lnmean[m0 + lrow]; rstd_r = lnrstd[m0 + lrow]; }

#define GLOAD(K0) do {                                                        \
    const float* sa_ = A  + (size_t)(m0 + lrow) * K + (K0) + lseg * 8;        \
    pa0 = *(const f32x4*)sa_;  pa1 = *(const f32x4*)(sa_ + 4);                \
    const float* sb_ = Bm + (size_t)(n0 + lrow) * K + (K0) + lseg * 8;        \
    pb0 = *(const f32x4*)sb_;  pb1 = *(const f32x4*)(sb_ + 4);                \
  } while (0)
#define SWRITE(BUF, K0) do {                                                  \
    f32x4 qa0 = pa0, qa1 = pa1;                                               \
    if (EPI == 1) {                                                           \
      const float* gp_ = gamma + (K0) + lseg * 8;                             \
      const float* bp_ = beta  + (K0) + lseg * 8;                             \
      f32x4 g0_ = *(const f32x4*)gp_, g1_ = *(const f32x4*)(gp_ + 4);         \
      f32x4 b0_ = *(const f32x4*)bp_, b1_ = *(const f32x4*)(bp_ + 4);         \
      _Pragma("unroll")                                                       \
      for (int r_ = 0; r_ < 4; r_++) {                                        \
        qa0[r_] = (qa0[r_] - mean_r) * rstd_r * g0_[r_] + b0_[r_];            \
        qa1[r_] = (qa1[r_] - mean_r) * rstd_r * g1_[r_] + b1_[r_];            \
      }                                                                       \
    }                                                                         \
    *(short8*)&As[(BUF)*2048 + lrow*32 + slot_w * 8] = cvt8(qa0, qa1);        \
    *(short8*)&Bs[(BUF)*2048 + lrow*32 + slot_w * 8] = cvt8(pb0, pb1);        \
  } while (0)

  // prologue: stage k=0 into buf 0 (full drain once is fine)
  GLOAD(0);
  SWRITE(0, 0);
  __syncthreads();

  int cur = 0;
  for (int k0 = 0; k0 < K; k0 += 32) {
    const bool more = (k0 + 32 < K);
    if (more) GLOAD(k0 + 32);          // in flight across barrier1
    short8 af[2], bfr[2];
#pragma unroll
    for (int ss = 0; ss < 2; ss++) {
      const int ra = wm*32 + ss*16 + lt;
      af[ss]  = *(const short8*)&As[cur*2048 + ra*32 + (g ^ ((ra & 3) ^ ((ra >> 2) & 3))) * 8];
      const int rb = wn*32 + ss*16 + lt;
      bfr[ss] = *(const short8*)&Bs[cur*2048 + rb*32 + (g ^ ((rb & 3) ^ ((rb >> 2) & 3))) * 8];
    }
#pragma unroll
    for (int i = 0; i < 2; i++)
#pragma unroll
      for (int j = 0; j < 2; j++)
        acc[i][j] = __builtin_amdgcn_mfma_f32_16x16x32_bf16(af[i], bfr[j], acc[i][j], 0, 0, 0);
    asm volatile("s_barrier" ::: "memory");
    if (more) {
      SWRITE(cur ^ 1, k0 + 32);
      asm volatile("s_waitcnt lgkmcnt(0)" ::: "memory");
    }
    asm volatile("s_barrier" ::: "memory");
    cur ^= 1;
  }

#pragma unroll
  for (int i = 0; i < 2; i++)
#pragma unroll
    for (int j = 0; j < 2; j++) {
      const int n  = n0 + wn*32 + j*16 + lt;
      const float bv = bias[n];
      const int mb = m0 + wm*32 + i*16 + g*4;
#pragma unroll
      for (int r = 0; r < 4; r++) {
        const int mm = mb + r;
        if (EPI == 0) {
          const float val = (acc[i][j][r] + bv) * 0.17677669529663687f;
          const int bb = mm >> 9, s = mm & 511;
          const int d = n >> 8, ql = (n >> 3) & 31, hh = n & 7;
          const int tt = s*2 + d;
          ((ushort*)outp)[((size_t)(bb*8 + hh) * 1024 + tt) * 32 + ql] = f2bf(val);
        } else {
          ((float*)outp)[(size_t)mm * N + n] = acc[i][j][r] + bv;
        }
      }
    }
#undef GLOAD
#undef SWRITE
}

// ---------------------------------------------------------------------------
// Fused dispatch 1: blocks 0..255 run prep (memory-bound); blocks 256..511
// run gemm0 (q-projection, compute-bound). Independent data -> overlap.
// ---------------------------------------------------------------------------
__global__ __launch_bounds__(256) void prep_gemm0(
    const float* __restrict__ keys, const float* __restrict__ values,
    ushort* __restrict__ kbf, ushort* __restrict__ vbf,
    const float* __restrict__ emb, const float* __restrict__ Wq,
    const float* __restrict__ bq, ushort* __restrict__ qbf)
{
  __shared__ __align__(16) char smem[17408];
  const int bi = blockIdx.x;
  if (bi < 256) {
    prep_body(smem, bi, keys, values, kbf, vbf);
  } else {
    const int gblk = bi - 256;           // 0..255 -> (mt 0..31, nt 0..7)
    const int m0 = (gblk & 31) * 64;
    const int n0 = (gblk >> 5) * 64;
    gemm_body<0>(smem, emb, Wq, bq, (void*)qbf, 2048, 512, 1024, m0, n0,
                 nullptr, nullptr, nullptr, nullptr);
  }
}

// ---------------------------------------------------------------------------
// gemm1 with fused LayerNorm on A (reads raw vo + per-row stats).
// ---------------------------------------------------------------------------
__global__ __launch_bounds__(256) void gemm1_ln(
    const float* __restrict__ vo, const float* __restrict__ Wo,
    const float* __restrict__ bo, float* __restrict__ outp,
    const float* __restrict__ lnmean, const float* __restrict__ lnrstd,
    const float* __restrict__ gamma, const float* __restrict__ beta)
{
  __shared__ __align__(16) char smem[16384];
  gemm_body<1>(smem, vo, Wo, bo, (void*)outp, 2048, 1024, 512,
               blockIdx.x * 64, blockIdx.y * 64, lnmean, lnrstd, gamma, beta);
}

// ---------------------------------------------------------------------------
// Attention (split-n), t-PAIR per wave. R14/R15 schedule byte-identical:
// 4-buffer LDS ocs ring (32KB), NS=8 (grid 1024), per pair [4 DMA then
// 8 K/V] pinned, pair-end vmcnt(8) retires exactly the 4 DMAs.
// ---------------------------------------------------------------------------
__global__ __launch_bounds__(256) void attn_kernel(
    const ushort* __restrict__ qbf, const ushort* __restrict__ kbf,
    const ushort* __restrict__ vbf, const float* __restrict__ ocs,
    float* __restrict__ pacc, float* __restrict__ pl, int nsteps)
{
#if OCS_ASYNC
  __shared__ float obuf[4][2048];   // ring: 4 x [2 tiles][32 rows][8 slots][4 f32]
#endif
  const int tid  = threadIdx.x;
  const int lane = tid & 63;
  const int id = blockIdx.x;
  const int h   = id & 7;
  const int ttp = (id >> 3) & 15;
  const int c   = id >> 7;
  const int b  = tid >> 6;
  const int wid0 = ((h << 5) + 2*ttp) * 4 + b;   // tile0's wid; tile1 = wid0+4
  const int t0 = ttp * 64;
  const int lt = lane & 15, g = lane >> 4;
  const int n_start = c * nsteps * 32;

  const ushort* qp = qbf + (size_t)(b*8 + h) * (1024*32);
  const ushort* kp = kbf + (size_t)(b*8 + h) * (2048*32);
  const ushort* vp = vbf + (size_t)(b*8 + h) * (32*2048);
  const float*  op = ocs + (size_t)h * (1024*2048);

#define NSX(I) (((I) < nsteps) ? (n_start + (I)*32) : n_start)

  const int srow = tid >> 3;
  const int scol = 4 * ((tid & 7) ^ (srow & 7));
  const float* sb0 = op + (size_t)(t0 + srow) * 2048 + scol;
  const float* sb1 = op + (size_t)(t0 + 32 + srow) * 2048 + scol;
#if OCS_ASYNC
  const int ldsw = (tid & 192) * 16;   // per-wave LDS byte base (lane*16 added by HW)
#define SL_ISSUE(STEP) do {                                                   \
    gl_lds16(sb0 + NSX(STEP), (float*)((char*)obuf + (((STEP) & 3) << 13) + ldsw));        \
    gl_lds16(sb1 + NSX(STEP), (float*)((char*)obuf + (((STEP) & 3) << 13) + 4096 + ldsw)); \
  } while (0)
  const int ro0 = lt * 128;            // ts=0 row byte offset
  const int ro1 = (16 + lt) * 128;     // ts=1
  const int c0x = ((2*g)     ^ (lt & 7)) * 16;   // sc0 slot bytes
  const int c1x = ((2*g + 1) ^ (lt & 7)) * 16;   // sc1 slot bytes
#define CO_READ(DST, TILE, STEP) do {                                         \
    const char* bb_ = (const char*)obuf + (((STEP) & 3) << 13) + ((TILE) << 12); \
    DST[0][0] = *(const f32x4*)(bb_ + ro0 + c0x);                             \
    DST[1][0] = *(const f32x4*)(bb_ + ro0 + c1x);                             \
    DST[0][1] = *(const f32x4*)(bb_ + ro1 + c0x);                             \
    DST[1][1] = *(const f32x4*)(bb_ + ro1 + c1x);                             \
  } while (0)
#define PAIR_SYNC() do {                                                      \
    __builtin_amdgcn_sched_barrier(0);                                        \
    asm volatile("s_waitcnt vmcnt(8)" ::: "memory");                          \
    __builtin_amdgcn_sched_barrier(0);                                        \
    __builtin_amdgcn_s_barrier();                                             \
  } while (0)
#else
#define SL_ISSUE(STEP)
#define CO_READ(DST, TILE, STEP) do {                                         \
    const int nn_ = NSX(STEP);                                                \
    const float* r0_ = op + (size_t)(t0 + (TILE)*32 + lt) * 2048 + nn_;       \
    const float* r1_ = op + (size_t)(t0 + (TILE)*32 + 16 + lt) * 2048 + nn_;  \
    DST[0][0] = *(const f32x4*)(r0_ + 8*g);                                   \
    DST[1][0] = *(const f32x4*)(r0_ + 8*g + 4);                               \
    DST[0][1] = *(const f32x4*)(r1_ + 8*g);                                   \
    DST[1][1] = *(const f32x4*)(r1_ + 8*g + 4);                               \
  } while (0)
#define PAIR_SYNC()
#endif

#define LD_KV(KD, VD, NN) do {                                                \
    KD[0] = *(const short8*)(kp + (size_t)((NN) + lt) * 32 + g*8);            \
    KD[1] = *(const short8*)(kp + (size_t)((NN) + 16 + lt) * 32 + g*8);       \
    VD[0] = *(const short8*)(vp + (size_t)lt * 2048 + (NN) + g*8);            \
    VD[1] = *(const short8*)(vp + (size_t)(16 + lt) * 2048 + (NN) + g*8);     \
  } while (0)

  short8 qf0[2], qf1[2];
#pragma unroll
  for (int ts = 0; ts < 2; ts++) {
    qf0[ts] = *(const short8*)(qp + (t0 + ts*16 + lt)*32 + g*8);
    qf1[ts] = *(const short8*)(qp + (t0 + 32 + ts*16 + lt)*32 + g*8);
  }

  f32x4 acc0[2][2] = {}, acc1[2][2] = {};
  float lsum0[2] = {0.f, 0.f}, lsum1[2] = {0.f, 0.f};
  const f32x4 fzero = {0.f, 0.f, 0.f, 0.f};

#define TSB(SC0, SC1, CO0, CO1, VLO, VHI, LS, ACCA, ACCB) do {                \
    float p0 = __expf(SC0[0] - CO0[0]);                                       \
    float p1 = __expf(SC0[1] - CO0[1]);                                       \
    float p2 = __expf(SC0[2] - CO0[2]);                                       \
    float p3 = __expf(SC0[3] - CO0[3]);                                       \
    float p4 = __expf(SC1[0] - CO1[0]);                                       \
    float p5 = __expf(SC1[1] - CO1[1]);                                       \
    float p6 = __expf(SC1[2] - CO1[2]);                                       \
    float p7 = __expf(SC1[3] - CO1[3]);                                       \
    LS += ((p0+p1)+(p2+p3)) + ((p4+p5)+(p6+p7));                              \
    union { unsigned int u[4]; short8 s; } pf;                                \
    pf.u[0] = (unsigned int)f2bf(p0) | ((unsigned int)f2bf(p1) << 16);        \
    pf.u[1] = (unsigned int)f2bf(p2) | ((unsigned int)f2bf(p3) << 16);        \
    pf.u[2] = (unsigned int)f2bf(p4) | ((unsigned int)f2bf(p5) << 16);        \
    pf.u[3] = (unsigned int)f2bf(p6) | ((unsigned int)f2bf(p7) << 16);        \
    ACCA = __builtin_amdgcn_mfma_f32_16x16x32_bf16(VLO, pf.s, ACCA, 0, 0, 0); \
    ACCB = __builtin_amdgcn_mfma_f32_16x16x32_bf16(VHI, pf.s, ACCB, 0, 0, 0); \
  } while (0)

#define STEPTILE(KC_, VC_, QFA, QFB, TILE, STEP, ACC, LS) do {                \
    f32x4 s0a = __builtin_amdgcn_mfma_f32_16x16x32_bf16(KC_[0], QFA, fzero, 0, 0, 0); \
    f32x4 s1a = __builtin_amdgcn_mfma_f32_16x16x32_bf16(KC_[1], QFA, fzero, 0, 0, 0); \
    f32x4 s0b = __builtin_amdgcn_mfma_f32_16x16x32_bf16(KC_[0], QFB, fzero, 0, 0, 0); \
    f32x4 s1b = __builtin_amdgcn_mfma_f32_16x16x32_bf16(KC_[1], QFB, fzero, 0, 0, 0); \
    f32x4 co[2][2];                                                           \
    CO_READ(co, TILE, STEP);                                                  \
    TSB(s0a, s1a, co[0][0], co[1][0], VC_[0], VC_[1], LS[0], ACC[0][0], ACC[0][1]); \
    TSB(s0b, s1b, co[0][1], co[1][1], VC_[0], VC_[1], LS[1], ACC[1][0], ACC[1][1]); \
  } while (0)

#define PAIR(SA_, KC, VC, KN, VN) do {                                        \
    const int sA_ = (SA_);                                                    \
    SL_ISSUE(sA_ + 2);                                                        \
    SL_ISSUE(sA_ + 3);                                                        \
    __builtin_amdgcn_sched_barrier(0);                                        \
    LD_KV(KN[0], VN[0], NSX(sA_ + 2));                                        \
    LD_KV(KN[1], VN[1], NSX(sA_ + 3));                                        \
    __builtin_amdgcn_sched_barrier(0);                                        \
    STEPTILE(KC[0], VC[0], qf0[0], qf0[1], 0, sA_,     acc0, lsum0);          \
    STEPTILE(KC[0], VC[0], qf1[0], qf1[1], 1, sA_,     acc1, lsum1);          \
    STEPTILE(KC[1], VC[1], qf0[0], qf0[1], 0, sA_ + 1, acc0, lsum0);          \
    STEPTILE(KC[1], VC[1], qf1[0], qf1[1], 1, sA_ + 1, acc1, lsum1);          \
    PAIR_SYNC();                                                              \
  } while (0)

  short8 KA[2][2], VA[2][2], KB[2][2], VB[2][2];

#if OCS_ASYNC
  SL_ISSUE(0); SL_ISSUE(1);
  __builtin_amdgcn_sched_barrier(0);
#endif
  LD_KV(KA[0], VA[0], NSX(0));
  LD_KV(KA[1], VA[1], NSX(1));
#if OCS_ASYNC
  __builtin_amdgcn_sched_barrier(0);
  asm volatile("s_waitcnt vmcnt(8)" ::: "memory");
  __builtin_amdgcn_s_barrier();
#endif

  for (int s = 0; s < nsteps; s += 4) {
    PAIR(s,     KA, VA, KB, VB);   // steps s,s+1; stage s+2,s+3
    PAIR(s + 2, KB, VB, KA, VA);   // steps s+2,s+3; stage s+4,s+5
  }
#undef PAIR
#undef STEPTILE
#undef TSB
#undef LD_KV
#undef CO_READ
#undef SL_ISSUE
#undef PAIR_SYNC
#undef NSX

  {
    float* pb0 = pacc + ((size_t)(c*1024 + wid0) * 4) * 256 + lane * 4;
    *(f32x4*)(pb0 + 0*256) = acc0[0][0];
    *(f32x4*)(pb0 + 1*256) = acc0[0][1];
    *(f32x4*)(pb0 + 2*256) = acc0[1][0];
    *(f32x4*)(pb0 + 3*256) = acc0[1][1];
    float* pb1 = pacc + ((size_t)(c*1024 + wid0 + 4) * 4) * 256 + lane * 4;
    *(f32x4*)(pb1 + 0*256) = acc1[0][0];
    *(f32x4*)(pb1 + 1*256) = acc1[0][1];
    *(f32x4*)(pb1 + 2*256) = acc1[1][0];
    *(f32x4*)(pb1 + 3*256) = acc1[1][1];
  }
#pragma unroll
  for (int ts = 0; ts < 2; ts++) {
    float L0 = lsum0[ts], L1 = lsum1[ts];
    L0 += __shfl_xor(L0, 16);  L0 += __shfl_xor(L0, 32);
    L1 += __shfl_xor(L1, 16);  L1 += __shfl_xor(L1, 32);
    if (g == 0) {
      pl[((size_t)(c*1024 + wid0)) * 32 + ts*16 + lt]     = L0;
      pl[((size_t)(c*1024 + wid0 + 4)) * 32 + ts*16 + lt] = L1;
    }
  }
}

// ---------------------------------------------------------------------------
// Combine partials across NS chunks, normalize, write vo[b*512+s][h*64+d*32+..]
// ---------------------------------------------------------------------------
__global__ __launch_bounds__(256) void combine_kernel(
    const float* __restrict__ pacc, const float* __restrict__ pl,
    float* __restrict__ vo, int NS)
{
  const int lane = threadIdx.x & 63;
  const int wid = blockIdx.x * 4 + (threadIdx.x >> 6);
  const int b  = wid & 3;
  const int tt = (wid >> 2) & 31;
  const int h  = wid >> 7;
  const int t0 = tt * 32;
  const int lt = lane & 15, g = lane >> 4;

  f32x4 acc[4] = {};
  float L[2] = {0.f, 0.f};
  for (int cc = 0; cc < NS; ++cc) {
    const float* pb = pacc + ((size_t)(cc*1024 + wid) * 4) * 256 + lane * 4;
#pragma unroll
    for (int q = 0; q < 4; q++) {
      f32x4 v = *(const f32x4*)(pb + q * 256);
#pragma unroll
      for (int r = 0; r < 4; r++) acc[q][r] += v[r];
    }
    L[0] += pl[((size_t)(cc*1024 + wid)) * 32 + lt];
    L[1] += pl[((size_t)(cc*1024 + wid)) * 32 + 16 + lt];
  }
#pragma unroll
  for (int ts = 0; ts < 2; ts++) {
    const float inv = 1.0f / L[ts];
    const int t = t0 + ts*16 + lt;
    const int s = t >> 1, d = t & 1;
    float* dst = vo + ((size_t)(b*512 + s) * 512) + h*64 + d*32;
#pragma unroll
    for (int vs = 0; vs < 2; vs++) {
      f32x4 o;
#pragma unroll
      for (int r = 0; r < 4; r++) o[r] = acc[ts*2 + vs][r] * inv;
      *(f32x4*)(dst + vs*16 + g*4) = o;
    }
  }
}

// ---------------------------------------------------------------------------
// LN stats: per row of vo (512 wide), compute mean and rstd. One wave/row.
// ---------------------------------------------------------------------------
__global__ __launch_bounds__(256) void ln_stats(
    const float* __restrict__ x_in, float* __restrict__ lnmean,
    float* __restrict__ lnrstd)
{
  const int row  = blockIdx.x * 4 + (threadIdx.x >> 6);
  const int lane = threadIdx.x & 63;
  const float* x = x_in + (size_t)row * 512 + lane * 8;
  f32x4 v0 = *(const f32x4*)x;
  f32x4 v1 = *(const f32x4*)(x + 4);
  float s = (v0[0]+v0[1]+v0[2]+v0[3]) + (v1[0]+v1[1]+v1[2]+v1[3]);
#pragma unroll
  for (int off = 1; off < 64; off <<= 1) s += __shfl_xor(s, off);
  const float mean = s * (1.0f/512.0f);
  float var = 0.f;
#pragma unroll
  for (int i = 0; i < 4; i++) {
    float d0 = v0[i]-mean, d1 = v1[i]-mean;
    var += d0*d0 + d1*d1;
  }
#pragma unroll
  for (int off = 1; off < 64; off <<= 1) var += __shfl_xor(var, off);
  const float rstd = rsqrtf(var * (1.0f/512.0f) + 1e-5f);
  if (lane == 0) {
    lnmean[row] = mean;
    lnrstd[row] = rstd;
  }
}

// ---------------------------------------------------------------------------
extern "C" void kernel_launch(void* const* d_in, const int* in_sizes, int n_in,
                              void* d_out, int out_size, void* d_ws, size_t ws_size,
                              hipStream_t stream)
{
  const float* emb    = (const float*)d_in[0];
  const float* keys   = (const float*)d_in[1];
  const float* values = (const float*)d_in[2];
  const float* ocs    = (const float*)d_in[3];
  const float* Wq     = (const float*)d_in[4];
  const float* bq     = (const float*)d_in[5];
  const float* Wo     = (const float*)d_in[6];
  const float* bo     = (const float*)d_in[7];
  const float* gamma  = (const float*)d_in[8];
  const float* beta   = (const float*)d_in[9];

  char* ws = (char*)d_ws;
  ushort* qbf = (ushort*)(ws);                    // 2 MB  [b,h,t,ql] bf16
  ushort* kbf = (ushort*)(ws + (2u << 20));       // 4 MB  [b,h,n',ql] bf16 (permuted tiles)
  ushort* vbf = (ushort*)(ws + (6u << 20));       // 4 MB  [b,h,vl,n] bf16
  float*  vo  = (float*) (ws + (10u << 20));      // 4 MB  [m,512] f32
  const size_t pbase = (size_t)14u << 20;

  int NS;
  if      (ws_size >= ((size_t)48u << 20)) NS = 8;   // pacc 32MB + pl 1MB + stats
  else if (ws_size >= ((size_t)31u << 20)) NS = 4;
  else if (ws_size >= ((size_t)23u << 20)) NS = 2;
  else                                     NS = 1;
  float* pacc = (float*)(ws + pbase);                              // NS*4MB
  float* pl   = (float*)(ws + pbase + (size_t)NS * (4u << 20));    // NS*128KB
  float* lnm  = (float*)(ws + pbase + (size_t)NS * (4u << 20) + (size_t)NS * (128u << 10));
  float* lnr  = lnm + 2048;
  const int nsteps = 2048 / (NS * 32);

  prep_gemm0<<<dim3(512), dim3(256), 0, stream>>>(keys, values, kbf, vbf,
                                                  emb, Wq, bq, qbf);
  attn_kernel<<<dim3(128 * NS), dim3(256), 0, stream>>>(qbf, kbf, vbf, ocs, pacc, pl, nsteps);
  combine_kernel<<<dim3(256), dim3(256), 0, stream>>>(pacc, pl, vo, NS);
  ln_stats<<<dim3(512), dim3(256), 0, stream>>>(vo, lnm, lnr);
  gemm1_ln<<<dim3(32, 16), dim3(256), 0, stream>>>(vo, Wo, bo, (float*)d_out,
                                                   lnm, lnr, gamma, beta);
}